// Round 3
// baseline (1122.108 us; speedup 1.0000x reference)
//
#include <hip/hip_runtime.h>
#include <hip/hip_bf16.h>

#define N_NODES 50000
#define E_EDGES 800000
#define IN_F 128
#define HIDF 64
#define HEADS 4
#define OUT_F 40
#define GROUPS 8
#define D_F 256
#define NEG 0.2f
#define LNEPS 1e-5f
#define POOL_CHUNK 128
#define POOL_BLOCKS ((N_NODES + POOL_CHUNK - 1) / POOL_CHUNK)   // 391
#define SCAN_T 256
#define SCAN_CHUNK ((N_NODES + SCAN_T - 1) / SCAN_T)            // 196

// canonical bf16 parameter buffer: element offsets
#define OFF_X    0
#define OFF_EW1  6400000
#define OFF_EB1  6408192
#define OFF_EG   6408256
#define OFF_EBE  6408320
#define OFF_EW2  6408384
#define OFF_EB2  6412480
#define OFF_C0W  6412544
#define OFF_C0AS 6428928
#define OFF_C0AD 6429184
#define OFF_C0B  6429440
#define OFF_C1W  6429696
#define OFF_C1AS 6495232
#define OFF_C1AD 6495488
#define OFF_C1B  6495744
#define OFF_C2W  6496000
#define OFF_C2AS 6561536
#define OFF_C2AD 6561792
#define OFF_C2B  6562048
#define OFF_DW1  6562304
#define OFF_DB1  6578688
#define OFF_DG   6578752
#define OFF_DBE  6578816
#define OFF_DW2  6578880
#define OFF_DB2  6581440
#define CANON_TOT 6581480

__device__ __constant__ int c_off[26] = {
    OFF_X, OFF_EW1, OFF_EB1, OFF_EG, OFF_EBE, OFF_EW2, OFF_EB2,
    OFF_C0W, OFF_C0AS, OFF_C0AD, OFF_C0B,
    OFF_C1W, OFF_C1AS, OFF_C1AD, OFF_C1B,
    OFF_C2W, OFF_C2AS, OFF_C2AD, OFF_C2B,
    OFF_DW1, OFF_DB1, OFF_DG, OFF_DBE, OFF_DW2, OFF_DB2, CANON_TOT};

__device__ __forceinline__ float bf2f(unsigned short u) {
    union { unsigned int i; float f; } v; v.i = ((unsigned int)u) << 16; return v.f;
}
__device__ __forceinline__ unsigned short f2bf(float f) {
    union { float f; unsigned int i; } v; v.f = f;
    unsigned int r = v.i + 0x7FFF + ((v.i >> 16) & 1);   // RNE
    return (unsigned short)(r >> 16);
}

// ---------- dtype flag: enc_g is all-ones. bf16 -> ushorts 0x3F80; fp32 -> (0x0000,0x3F80) ----------
__global__ void flag_k(const unsigned short* __restrict__ encg, int* __restrict__ flag) {
    if (threadIdx.x == 0 && blockIdx.x == 0) {
        unsigned short a = encg[0], b = encg[1];
        int f = 0;                          // default: bf16
        if (a == 0x0000 && b == 0x3F80) f = 1;  // fp32 little-endian 1.0f
        *flag = f;
    }
}

// ---------- probe: pre-fill d_out with 1.0 (overwritten by dec_k if pipeline completes) ----------
__global__ void probe_k(void* __restrict__ outp, const int* __restrict__ flag) {
    int i = blockIdx.x * 256 + threadIdx.x;
    if (i >= GROUPS * OUT_F) return;
    if (*flag == 0) ((unsigned short*)outp)[i] = 0x3F80;
    else            ((float*)outp)[i] = 1.0f;
}

// ---------- canonicalize all float tensors into bf16 canon buffer ----------
struct SP { const void* q[25]; };
__global__ __launch_bounds__(256) void convert_k(SP sp, const int* __restrict__ flag,
                                                 unsigned short* __restrict__ canon) {
    int i = blockIdx.x * 256 + threadIdx.x;
    if (i >= CANON_TOT) return;
    int t = 0;
    while (i >= c_off[t + 1]) ++t;
    int j = i - c_off[t];
    const void* s = sp.q[t];
    unsigned short v;
    if (*flag == 0) v = ((const unsigned short*)s)[j];
    else            v = f2bf(((const float*)s)[j]);
    canon[i] = v;
}

// ---------------- encoder: h0 = relu(LN(x@w1+b1))@w2+b2, wave per node ----------------
__global__ __launch_bounds__(256) void encoder_k(const unsigned short* __restrict__ canon,
                                                 unsigned short* __restrict__ h0) {
    const unsigned short* x  = canon + OFF_X;
    const unsigned short* w1 = canon + OFF_EW1;
    const unsigned short* b1 = canon + OFF_EB1;
    const unsigned short* gam = canon + OFF_EG;
    const unsigned short* bet = canon + OFF_EBE;
    const unsigned short* w2 = canon + OFF_EW2;
    const unsigned short* b2 = canon + OFF_EB2;
    __shared__ float w1s[IN_F * HIDF];
    __shared__ float w2s[HIDF * HIDF];
    int tid = threadIdx.x;
    for (int i = tid * 4; i < IN_F * HIDF; i += 256 * 4) {
        ushort4 u = *(const ushort4*)(w1 + i);
        w1s[i] = bf2f(u.x); w1s[i + 1] = bf2f(u.y); w1s[i + 2] = bf2f(u.z); w1s[i + 3] = bf2f(u.w);
    }
    for (int i = tid * 4; i < HIDF * HIDF; i += 256 * 4) {
        ushort4 u = *(const ushort4*)(w2 + i);
        w2s[i] = bf2f(u.x); w2s[i + 1] = bf2f(u.y); w2s[i + 2] = bf2f(u.z); w2s[i + 3] = bf2f(u.w);
    }
    __syncthreads();
    int wave = tid >> 6, lane = tid & 63;
    int n = blockIdx.x * 4 + wave;
    if (n >= N_NODES) return;
    const unsigned short* xr = x + (size_t)n * IN_F;
    float x0 = bf2f(xr[lane]);
    float x1 = bf2f(xr[64 + lane]);
    float acc = bf2f(b1[lane]);
#pragma unroll 8
    for (int k = 0; k < 64; ++k) acc = fmaf(__shfl(x0, k), w1s[k * 64 + lane], acc);
#pragma unroll 8
    for (int k = 0; k < 64; ++k) acc = fmaf(__shfl(x1, k), w1s[(64 + k) * 64 + lane], acc);
    float s = acc;
#pragma unroll
    for (int off = 32; off > 0; off >>= 1) s += __shfl_xor(s, off);
    float mean = s * (1.0f / 64.0f);
    float d = acc - mean;
    float vs = d * d;
#pragma unroll
    for (int off = 32; off > 0; off >>= 1) vs += __shfl_xor(vs, off);
    float rstd = rsqrtf(vs * (1.0f / 64.0f) + LNEPS);
    float val = bf2f(gam[lane]) * d * rstd + bf2f(bet[lane]);
    val = val > 0.f ? val : val * 0.f;   // relu, NaN-transparent
    float acc2 = bf2f(b2[lane]);
#pragma unroll 8
    for (int k = 0; k < 64; ++k) acc2 = fmaf(__shfl(val, k), w2s[k * 64 + lane], acc2);
    h0[(size_t)n * HIDF + lane] = f2bf(acc2);
}

// ---------------- CSR build ----------------
__global__ void deg_init_k(int* __restrict__ deg) {
    int i = blockIdx.x * 256 + threadIdx.x;
    if (i < N_NODES) deg[i] = 1;  // self-loop
}
__global__ void deg_count_k(const int* __restrict__ dstI, int* __restrict__ deg) {
    int i = blockIdx.x * 256 + threadIdx.x;
    if (i < E_EDGES) atomicAdd(&deg[dstI[i]], 1);
}
__global__ __launch_bounds__(SCAN_T) void scan_k(const int* __restrict__ deg,
                                                 int* __restrict__ rowp, int* __restrict__ cursor) {
    int tid = threadIdx.x, lane = tid & 63, wv = tid >> 6;
    int c0 = tid * SCAN_CHUNK; if (c0 > N_NODES) c0 = N_NODES;
    int c1 = c0 + SCAN_CHUNK; if (c1 > N_NODES) c1 = N_NODES;
    int s = 0;
    for (int i = c0; i < c1; ++i) s += deg[i];
    int inc = s;
#pragma unroll
    for (int off = 1; off < 64; off <<= 1) { int t = __shfl_up(inc, off); if (lane >= off) inc += t; }
    __shared__ int wsum[SCAN_T / 64];
    if (lane == 63) wsum[wv] = inc;
    __syncthreads();
    int wo = 0;
    for (int w = 0; w < wv; ++w) wo += wsum[w];
    int run = inc - s + wo;   // exclusive prefix of this thread's chunk
    for (int i = c0; i < c1; ++i) { rowp[i] = run; cursor[i] = run; run += deg[i]; }
    if (tid == SCAN_T - 1) rowp[N_NODES] = run;
}
__global__ void fill_k(const int* __restrict__ srcI, const int* __restrict__ dstI,
                       int* __restrict__ cursor, int* __restrict__ colx) {
    int i = blockIdx.x * 256 + threadIdx.x;
    if (i >= E_EDGES + N_NODES) return;
    int s, d;
    if (i < E_EDGES) { s = srcI[i]; d = dstI[i]; } else { s = i - E_EDGES; d = s; }
    int slot = atomicAdd(&cursor[d], 1);
    colx[slot] = s;
}

// ---------------- matmul: C[M,256] = A[M,K] @ W[K,256], bf16 in, fp32 acc, bf16 out ----------------
__global__ __launch_bounds__(256) void matmul_k(
    const unsigned short* __restrict__ A, const unsigned short* __restrict__ W,
    unsigned short* __restrict__ C, int M, int K) {
    __shared__ float As[16 * 68];
    __shared__ float Ws[16 * 64];
    int tid = threadIdx.x;
    int row0 = blockIdx.y * 64;
    int col0 = blockIdx.x * 64;
    int tx = tid & 15, ty = tid >> 4;
    float acc[4][4] = {};
    int r = tid >> 2, kq = (tid & 3) * 4;
    int wk = tid >> 4, wn = (tid & 15) * 4;
    for (int kt = 0; kt < K; kt += 16) {
        ushort4 au = make_ushort4(0, 0, 0, 0);
        int grow = row0 + r;
        if (grow < M) au = *(const ushort4*)(A + (size_t)grow * K + kt + kq);
        As[(kq + 0) * 68 + r] = bf2f(au.x);
        As[(kq + 1) * 68 + r] = bf2f(au.y);
        As[(kq + 2) * 68 + r] = bf2f(au.z);
        As[(kq + 3) * 68 + r] = bf2f(au.w);
        ushort4 wu = *(const ushort4*)(W + (size_t)(kt + wk) * D_F + col0 + wn);
        *(float4*)&Ws[wk * 64 + wn] = make_float4(bf2f(wu.x), bf2f(wu.y), bf2f(wu.z), bf2f(wu.w));
        __syncthreads();
#pragma unroll
        for (int k = 0; k < 16; ++k) {
            float4 a = *(const float4*)&As[k * 68 + (ty << 2)];
            float4 b = *(const float4*)&Ws[(k << 6) + (tx << 2)];
            acc[0][0] = fmaf(a.x, b.x, acc[0][0]);
            acc[0][1] = fmaf(a.x, b.y, acc[0][1]);
            acc[0][2] = fmaf(a.x, b.z, acc[0][2]);
            acc[0][3] = fmaf(a.x, b.w, acc[0][3]);
            acc[1][0] = fmaf(a.y, b.x, acc[1][0]);
            acc[1][1] = fmaf(a.y, b.y, acc[1][1]);
            acc[1][2] = fmaf(a.y, b.z, acc[1][2]);
            acc[1][3] = fmaf(a.y, b.w, acc[1][3]);
            acc[2][0] = fmaf(a.z, b.x, acc[2][0]);
            acc[2][1] = fmaf(a.z, b.y, acc[2][1]);
            acc[2][2] = fmaf(a.z, b.z, acc[2][2]);
            acc[2][3] = fmaf(a.z, b.w, acc[2][3]);
            acc[3][0] = fmaf(a.w, b.x, acc[3][0]);
            acc[3][1] = fmaf(a.w, b.y, acc[3][1]);
            acc[3][2] = fmaf(a.w, b.z, acc[3][2]);
            acc[3][3] = fmaf(a.w, b.w, acc[3][3]);
        }
        __syncthreads();
    }
#pragma unroll
    for (int i = 0; i < 4; ++i) {
        int grow = row0 + ty * 4 + i;
        if (grow < M) {
            ushort4 o;
            o.x = f2bf(acc[i][0]); o.y = f2bf(acc[i][1]);
            o.z = f2bf(acc[i][2]); o.w = f2bf(acc[i][3]);
            *(ushort4*)(C + (size_t)grow * D_F + col0 + tx * 4) = o;
        }
    }
}

// ---------------- attention logits ----------------
__global__ __launch_bounds__(256) void att_k(
    const unsigned short* __restrict__ h2, const unsigned short* __restrict__ a_s,
    const unsigned short* __restrict__ a_d, float* __restrict__ alS, float* __restrict__ alD) {
    int tid = threadIdx.x, wave = tid >> 6, lane = tid & 63;
    int n = blockIdx.x * 4 + wave;
    if (n >= N_NODES) return;
    int h = lane >> 4, j = (lane & 15) * 4;
    ushort4 hu = *(const ushort4*)(h2 + (size_t)n * D_F + h * 64 + j);
    ushort4 su = *(const ushort4*)(a_s + h * 64 + j);
    ushort4 du = *(const ushort4*)(a_d + h * 64 + j);
    float h0 = bf2f(hu.x), h1 = bf2f(hu.y), h2v = bf2f(hu.z), h3 = bf2f(hu.w);
    float ps = h0 * bf2f(su.x) + h1 * bf2f(su.y) + h2v * bf2f(su.z) + h3 * bf2f(su.w);
    float pd = h0 * bf2f(du.x) + h1 * bf2f(du.y) + h2v * bf2f(du.z) + h3 * bf2f(du.w);
#pragma unroll
    for (int off = 1; off < 16; off <<= 1) { ps += __shfl_xor(ps, off); pd += __shfl_xor(pd, off); }
    if ((lane & 15) == 0) { alS[n * 4 + h] = ps; alD[n * 4 + h] = pd; }
}

// ---------------- GAT aggregate + bias + ELU: wave per dst node ----------------
__global__ __launch_bounds__(256) void agg_k(
    const unsigned short* __restrict__ h2, const int* __restrict__ rowp, const int* __restrict__ colx,
    const float* __restrict__ alS, const float* __restrict__ alD,
    const unsigned short* __restrict__ bias, unsigned short* __restrict__ out) {
    int tid = threadIdx.x, wave = tid >> 6, lane = tid & 63;
    int n = blockIdx.x * 4 + wave;
    if (n >= N_NODES) return;
    int start = rowp[n], end = rowp[n + 1];
    float4 ad = *(const float4*)(alD + (size_t)n * 4);
    float m0 = -1e30f, m1 = -1e30f, m2 = -1e30f, m3 = -1e30f;
    for (int j = start + lane; j < end; j += 64) {
        int s = colx[j];
        float4 as = *(const float4*)(alS + (size_t)s * 4);
        float e0 = as.x + ad.x; e0 = e0 > 0.f ? e0 : NEG * e0;
        float e1 = as.y + ad.y; e1 = e1 > 0.f ? e1 : NEG * e1;
        float e2 = as.z + ad.z; e2 = e2 > 0.f ? e2 : NEG * e2;
        float e3 = as.w + ad.w; e3 = e3 > 0.f ? e3 : NEG * e3;
        m0 = fmaxf(m0, e0); m1 = fmaxf(m1, e1); m2 = fmaxf(m2, e2); m3 = fmaxf(m3, e3);
    }
#pragma unroll
    for (int off = 1; off < 64; off <<= 1) {
        m0 = fmaxf(m0, __shfl_xor(m0, off));
        m1 = fmaxf(m1, __shfl_xor(m1, off));
        m2 = fmaxf(m2, __shfl_xor(m2, off));
        m3 = fmaxf(m3, __shfl_xor(m3, off));
    }
    float l0 = 0.f, l1 = 0.f, l2 = 0.f, l3 = 0.f;
    for (int j = start + lane; j < end; j += 64) {
        int s = colx[j];
        float4 as = *(const float4*)(alS + (size_t)s * 4);
        float e0 = as.x + ad.x; e0 = e0 > 0.f ? e0 : NEG * e0;
        float e1 = as.y + ad.y; e1 = e1 > 0.f ? e1 : NEG * e1;
        float e2 = as.z + ad.z; e2 = e2 > 0.f ? e2 : NEG * e2;
        float e3 = as.w + ad.w; e3 = e3 > 0.f ? e3 : NEG * e3;
        l0 += __expf(e0 - m0); l1 += __expf(e1 - m1); l2 += __expf(e2 - m2); l3 += __expf(e3 - m3);
    }
#pragma unroll
    for (int off = 1; off < 64; off <<= 1) {
        l0 += __shfl_xor(l0, off); l1 += __shfl_xor(l1, off);
        l2 += __shfl_xor(l2, off); l3 += __shfl_xor(l3, off);
    }
    float r0 = 1.f / (l0 + 1e-16f), r1 = 1.f / (l1 + 1e-16f);
    float r2 = 1.f / (l2 + 1e-16f), r3 = 1.f / (l3 + 1e-16f);
    float a0 = 0.f, a1 = 0.f, a2 = 0.f, a3 = 0.f;
    for (int j = start; j < end; ++j) {
        int s = colx[j];
        float4 as = *(const float4*)(alS + (size_t)s * 4);
        float e0 = as.x + ad.x; e0 = e0 > 0.f ? e0 : NEG * e0; float w0 = __expf(e0 - m0) * r0;
        float e1 = as.y + ad.y; e1 = e1 > 0.f ? e1 : NEG * e1; float w1 = __expf(e1 - m1) * r1;
        float e2 = as.z + ad.z; e2 = e2 > 0.f ? e2 : NEG * e2; float w2 = __expf(e2 - m2) * r2;
        float e3 = as.w + ad.w; e3 = e3 > 0.f ? e3 : NEG * e3; float w3 = __expf(e3 - m3) * r3;
        const unsigned short* hr = h2 + (size_t)s * D_F;
        a0 = fmaf(w0, bf2f(hr[lane]), a0);
        a1 = fmaf(w1, bf2f(hr[64 + lane]), a1);
        a2 = fmaf(w2, bf2f(hr[128 + lane]), a2);
        a3 = fmaf(w3, bf2f(hr[192 + lane]), a3);
    }
    unsigned short* orow = out + (size_t)n * D_F;
    float v0 = a0 + bf2f(bias[lane]);       v0 = v0 > 0.f ? v0 : __expf(v0) - 1.f;
    float v1 = a1 + bf2f(bias[64 + lane]);  v1 = v1 > 0.f ? v1 : __expf(v1) - 1.f;
    float v2 = a2 + bf2f(bias[128 + lane]); v2 = v2 > 0.f ? v2 : __expf(v2) - 1.f;
    float v3 = a3 + bf2f(bias[192 + lane]); v3 = v3 > 0.f ? v3 : __expf(v3) - 1.f;
    orow[lane] = f2bf(v0); orow[64 + lane] = f2bf(v1);
    orow[128 + lane] = f2bf(v2); orow[192 + lane] = f2bf(v3);
}

// ---------------- pool: per-block partial sums (no atomics) ----------------
__global__ __launch_bounds__(256) void pool_k(const unsigned short* __restrict__ h,
                                              const int* __restrict__ batch,
                                              float* __restrict__ part, int* __restrict__ pcnt) {
    __shared__ float sums[GROUPS * D_F];
    __shared__ int cnts[GROUPS];
    int tid = threadIdx.x;
    for (int i = tid; i < GROUPS * D_F; i += 256) sums[i] = 0.f;
    if (tid < GROUPS) cnts[tid] = 0;
    __syncthreads();
    int n0 = blockIdx.x * POOL_CHUNK;
    int n1 = n0 + POOL_CHUNK; if (n1 > N_NODES) n1 = N_NODES;
    for (int n = n0; n < n1; ++n) {
        int b = batch[n];
        sums[b * D_F + tid] += bf2f(h[(size_t)n * D_F + tid]);
        if (tid == 0) cnts[b]++;
    }
    __syncthreads();
    float* po = part + (size_t)blockIdx.x * (GROUPS * D_F);
    for (int i = tid; i < GROUPS * D_F; i += 256) po[i] = sums[i];
    if (tid < GROUPS) pcnt[blockIdx.x * GROUPS + tid] = cnts[tid];
}

// ---------------- reduce partials ----------------
__global__ __launch_bounds__(256) void reduce_k(const float* __restrict__ part,
                                                const int* __restrict__ pcnt,
                                                float* __restrict__ gsum, int* __restrict__ gcnt) {
    int g = blockIdx.x, c = threadIdx.x;
    float s = 0.f;
    for (int b = 0; b < POOL_BLOCKS; ++b) s += part[(size_t)b * (GROUPS * D_F) + g * D_F + c];
    gsum[g * D_F + c] = s;
    if (threadIdx.x < 64) {
        int lane = threadIdx.x;
        int cn = 0;
        for (int b = lane; b < POOL_BLOCKS; b += 64) cn += pcnt[b * GROUPS + g];
#pragma unroll
        for (int off = 1; off < 64; off <<= 1) cn += __shfl_xor(cn, off);
        if (lane == 0) gcnt[g] = cn;
    }
}

// ---------------- decoder: wave per group, 2 blocks x 4 waves ----------------
__global__ __launch_bounds__(256) void dec_k(const float* __restrict__ gsum, const int* __restrict__ gcnt,
    const unsigned short* __restrict__ canon, const int* __restrict__ flag,
    void* __restrict__ outp) {
    const unsigned short* w1 = canon + OFF_DW1;
    const unsigned short* b1 = canon + OFF_DB1;
    const unsigned short* gam = canon + OFF_DG;
    const unsigned short* bet = canon + OFF_DBE;
    const unsigned short* w2 = canon + OFF_DW2;
    const unsigned short* b2 = canon + OFF_DB2;
    int tid = threadIdx.x, grp = blockIdx.x * 4 + (tid >> 6), lane = tid & 63;
    if (grp >= GROUPS) return;
    float inv = 1.0f / fmaxf((float)gcnt[grp], 1.0f);
    float p[4];
#pragma unroll
    for (int i = 0; i < 4; ++i) p[i] = gsum[grp * D_F + i * 64 + lane] * inv;
    float acc = bf2f(b1[lane]);
#pragma unroll
    for (int i = 0; i < 4; ++i)
        for (int k = 0; k < 64; ++k)
            acc = fmaf(__shfl(p[i], k), bf2f(w1[(i * 64 + k) * 64 + lane]), acc);
    float s = acc;
#pragma unroll
    for (int off = 32; off > 0; off >>= 1) s += __shfl_xor(s, off);
    float mean = s * (1.0f / 64.0f);
    float d = acc - mean;
    float vs = d * d;
#pragma unroll
    for (int off = 32; off > 0; off >>= 1) vs += __shfl_xor(vs, off);
    float rstd = rsqrtf(vs * (1.0f / 64.0f) + LNEPS);
    float val = bf2f(gam[lane]) * d * rstd + bf2f(bet[lane]);
    val = val > 0.f ? val : val * 0.f;   // relu, NaN-transparent
    int cl = (lane < OUT_F) ? lane : 0;
    float acc2 = 0.f;
    for (int k = 0; k < 64; ++k) {
        float wv = bf2f(w2[k * OUT_F + cl]);
        acc2 = fmaf(__shfl(val, k), wv, acc2);
    }
    if (lane < OUT_F) {
        float res = acc2 + bf2f(b2[lane]);
        if (*flag == 0) ((unsigned short*)outp)[grp * OUT_F + lane] = f2bf(res);
        else            ((float*)outp)[grp * OUT_F + lane] = res;
    }
}

extern "C" void kernel_launch(void* const* d_in, const int* in_sizes, int n_in,
                              void* d_out, int out_size, void* d_ws, size_t ws_size,
                              hipStream_t stream) {
    const int* ei    = (const int*)d_in[1];
    const int* batch = (const int*)d_in[2];

    // workspace layout, total ~73.3 MB
    char* p = (char*)d_ws;
    unsigned short* canon = (unsigned short*)p; p += (size_t)CANON_TOT * 2 + 16;        // 13.2 MB
    unsigned short* bufA = (unsigned short*)p; p += (size_t)N_NODES * D_F * 2;          // 25.6 MB
    unsigned short* bufB = (unsigned short*)p; p += (size_t)N_NODES * D_F * 2;          // 25.6 MB
    float* alS  = (float*)p; p += (size_t)N_NODES * 4 * 4;                              // 0.8 MB
    float* alD  = (float*)p; p += (size_t)N_NODES * 4 * 4;                              // 0.8 MB
    float* part = (float*)p; p += (size_t)POOL_BLOCKS * GROUPS * D_F * 4;               // 3.2 MB
    int* pcnt   = (int*)p;   p += (size_t)POOL_BLOCKS * GROUPS * 4;
    float* gsum = (float*)p; p += GROUPS * D_F * 4;
    int* gcnt   = (int*)p;   p += 16 * 4;
    int* deg    = (int*)p;   p += (size_t)N_NODES * 4;
    int* rowp   = (int*)p;   p += (size_t)(N_NODES + 4) * 4;
    int* cursor = (int*)p;   p += (size_t)N_NODES * 4;
    int* colx   = (int*)p;   p += (size_t)(E_EDGES + N_NODES) * 4;
    int* flag   = (int*)p;   p += 16;

    const int* srcI = ei;
    const int* dstI = ei + E_EDGES;

    SP sp;
    sp.q[0] = d_in[0];
    for (int t = 1; t < 25; ++t) sp.q[t] = d_in[t + 2];   // skip edge_index, batch

    int nwb = (N_NODES + 3) / 4;
    int nb256 = (N_NODES + 255) / 256;

    flag_k<<<1, 64, 0, stream>>>((const unsigned short*)d_in[5], flag);
    probe_k<<<2, 256, 0, stream>>>(d_out, flag);
    convert_k<<<(CANON_TOT + 255) / 256, 256, 0, stream>>>(sp, flag, canon);

    encoder_k<<<nwb, 256, 0, stream>>>(canon, bufA);

    deg_init_k<<<nb256, 256, 0, stream>>>(deg);
    deg_count_k<<<(E_EDGES + 255) / 256, 256, 0, stream>>>(dstI, deg);
    scan_k<<<1, SCAN_T, 0, stream>>>(deg, rowp, cursor);
    fill_k<<<(E_EDGES + N_NODES + 255) / 256, 256, 0, stream>>>(srcI, dstI, cursor, colx);

    dim3 mmg(4, (N_NODES + 63) / 64);
    matmul_k<<<mmg, 256, 0, stream>>>(bufA, canon + OFF_C0W, bufB, N_NODES, HIDF);
    att_k<<<nwb, 256, 0, stream>>>(bufB, canon + OFF_C0AS, canon + OFF_C0AD, alS, alD);
    agg_k<<<nwb, 256, 0, stream>>>(bufB, rowp, colx, alS, alD, canon + OFF_C0B, bufA);

    matmul_k<<<mmg, 256, 0, stream>>>(bufA, canon + OFF_C1W, bufB, N_NODES, D_F);
    att_k<<<nwb, 256, 0, stream>>>(bufB, canon + OFF_C1AS, canon + OFF_C1AD, alS, alD);
    agg_k<<<nwb, 256, 0, stream>>>(bufB, rowp, colx, alS, alD, canon + OFF_C1B, bufA);

    matmul_k<<<mmg, 256, 0, stream>>>(bufA, canon + OFF_C2W, bufB, N_NODES, D_F);
    att_k<<<nwb, 256, 0, stream>>>(bufB, canon + OFF_C2AS, canon + OFF_C2AD, alS, alD);
    agg_k<<<nwb, 256, 0, stream>>>(bufB, rowp, colx, alS, alD, canon + OFF_C2B, bufA);

    pool_k<<<POOL_BLOCKS, 256, 0, stream>>>(bufA, batch, part, pcnt);
    reduce_k<<<GROUPS, 256, 0, stream>>>(part, pcnt, gsum, gcnt);
    dec_k<<<2, 256, 0, stream>>>(gsum, gcnt, canon, flag, d_out);
}

// Round 4
// 1027.018 us; speedup vs baseline: 1.0926x; 1.0926x over previous
//
#include <hip/hip_runtime.h>
#include <hip/hip_bf16.h>

#define N_NODES 50000
#define E_EDGES 800000
#define IN_F 128
#define HIDF 64
#define HEADS 4
#define OUT_F 40
#define GROUPS 8
#define D_F 256
#define NEG 0.2f
#define LNEPS 1e-5f
#define POOL_CHUNK 128
#define POOL_BLOCKS ((N_NODES + POOL_CHUNK - 1) / POOL_CHUNK)   // 391
#define SCAN_T 256
#define SCAN_CHUNK ((N_NODES + SCAN_T - 1) / SCAN_T)            // 196

// canonical bf16 parameter buffer: element offsets
#define OFF_X    0
#define OFF_EW1  6400000
#define OFF_EB1  6408192
#define OFF_EG   6408256
#define OFF_EBE  6408320
#define OFF_EW2  6408384
#define OFF_EB2  6412480
#define OFF_C0W  6412544
#define OFF_C0AS 6428928
#define OFF_C0AD 6429184
#define OFF_C0B  6429440
#define OFF_C1W  6429696
#define OFF_C1AS 6495232
#define OFF_C1AD 6495488
#define OFF_C1B  6495744
#define OFF_C2W  6496000
#define OFF_C2AS 6561536
#define OFF_C2AD 6561792
#define OFF_C2B  6562048
#define OFF_DW1  6562304
#define OFF_DB1  6578688
#define OFF_DG   6578752
#define OFF_DBE  6578816
#define OFF_DW2  6578880
#define OFF_DB2  6581440
#define CANON_TOT 6581480

__device__ __constant__ int c_off[26] = {
    OFF_X, OFF_EW1, OFF_EB1, OFF_EG, OFF_EBE, OFF_EW2, OFF_EB2,
    OFF_C0W, OFF_C0AS, OFF_C0AD, OFF_C0B,
    OFF_C1W, OFF_C1AS, OFF_C1AD, OFF_C1B,
    OFF_C2W, OFF_C2AS, OFF_C2AD, OFF_C2B,
    OFF_DW1, OFF_DB1, OFF_DG, OFF_DBE, OFF_DW2, OFF_DB2, CANON_TOT};

typedef __attribute__((ext_vector_type(8))) short bf16x8;
typedef __attribute__((ext_vector_type(4))) float f32x4;

__device__ __forceinline__ float bf2f(unsigned short u) {
    union { unsigned int i; float f; } v; v.i = ((unsigned int)u) << 16; return v.f;
}
__device__ __forceinline__ unsigned short f2bf(float f) {
    union { float f; unsigned int i; } v; v.f = f;
    unsigned int r = v.i + 0x7FFF + ((v.i >> 16) & 1);   // RNE
    return (unsigned short)(r >> 16);
}

// ---------- dtype flag: enc_g is all-ones. bf16 -> 0x3F80; fp32 -> (0x0000,0x3F80) ----------
__global__ void flag_k(const unsigned short* __restrict__ encg, int* __restrict__ flag) {
    if (threadIdx.x == 0 && blockIdx.x == 0) {
        unsigned short a = encg[0], b = encg[1];
        int f = 0;
        if (a == 0x0000 && b == 0x3F80) f = 1;
        *flag = f;
    }
}

// ---------- canonicalize all float tensors into bf16 canon buffer ----------
struct SP { const void* q[25]; };
__global__ __launch_bounds__(256) void convert_k(SP sp, const int* __restrict__ flag,
                                                 unsigned short* __restrict__ canon) {
    int i = blockIdx.x * 256 + threadIdx.x;
    if (i >= CANON_TOT) return;
    int t = 0;
    while (i >= c_off[t + 1]) ++t;
    int j = i - c_off[t];
    const void* s = sp.q[t];
    unsigned short v;
    if (*flag == 0) v = ((const unsigned short*)s)[j];
    else            v = f2bf(((const float*)s)[j]);
    canon[i] = v;
}

// ---------- transpose conv W matrices: W[K,256] -> Wt[256,K] ----------
__global__ void wt_k(const unsigned short* __restrict__ canon,
                     unsigned short* __restrict__ wt0, unsigned short* __restrict__ wt1,
                     unsigned short* __restrict__ wt2) {
    int i = blockIdx.x * 256 + threadIdx.x;
    if (i < 64 * 256) {
        int k = i >> 8, n = i & 255;
        wt0[n * 64 + k] = canon[OFF_C0W + i];
    }
    if (i < 65536) {
        int k = i >> 8, n = i & 255;
        wt1[n * 256 + k] = canon[OFF_C1W + i];
        wt2[n * 256 + k] = canon[OFF_C2W + i];
    }
}

// ---------------- encoder: 64 nodes/block, 16/wave in ILP pairs ----------------
__global__ __launch_bounds__(256) void encoder_k(const unsigned short* __restrict__ canon,
                                                 unsigned short* __restrict__ h0) {
    const unsigned short* x   = canon + OFF_X;
    const unsigned short* w1  = canon + OFF_EW1;
    const unsigned short* pb1 = canon + OFF_EB1;
    const unsigned short* gam = canon + OFF_EG;
    const unsigned short* bet = canon + OFF_EBE;
    const unsigned short* w2  = canon + OFF_EW2;
    const unsigned short* pb2 = canon + OFF_EB2;
    __shared__ float w1s[IN_F * HIDF];
    __shared__ float w2s[HIDF * HIDF];
    int tid = threadIdx.x;
    for (int i = tid * 4; i < IN_F * HIDF; i += 1024) {
        ushort4 u = *(const ushort4*)(w1 + i);
        w1s[i] = bf2f(u.x); w1s[i + 1] = bf2f(u.y); w1s[i + 2] = bf2f(u.z); w1s[i + 3] = bf2f(u.w);
    }
    for (int i = tid * 4; i < HIDF * HIDF; i += 1024) {
        ushort4 u = *(const ushort4*)(w2 + i);
        w2s[i] = bf2f(u.x); w2s[i + 1] = bf2f(u.y); w2s[i + 2] = bf2f(u.z); w2s[i + 3] = bf2f(u.w);
    }
    __syncthreads();
    int wave = tid >> 6, lane = tid & 63;
    float bias1 = bf2f(pb1[lane]);
    float g = bf2f(gam[lane]), be = bf2f(bet[lane]);
    float bias2 = bf2f(pb2[lane]);
    int nbase = blockIdx.x * 64 + wave * 16;
    for (int i = 0; i < 16; i += 2) {
        int na = nbase + i, nb2 = nbase + i + 1;
        if (na >= N_NODES) return;
        bool vb = nb2 < N_NODES;
        const unsigned short* xa = x + (size_t)na * IN_F;
        const unsigned short* xb = x + (size_t)(vb ? nb2 : na) * IN_F;
        float xa0 = bf2f(xa[lane]), xa1 = bf2f(xa[64 + lane]);
        float xb0 = bf2f(xb[lane]), xb1 = bf2f(xb[64 + lane]);
        float A = bias1, B = bias1;
#pragma unroll 8
        for (int k = 0; k < 64; ++k) {
            float wv = w1s[k * 64 + lane];
            A = fmaf(__shfl(xa0, k), wv, A);
            B = fmaf(__shfl(xb0, k), wv, B);
        }
#pragma unroll 8
        for (int k = 0; k < 64; ++k) {
            float wv = w1s[(64 + k) * 64 + lane];
            A = fmaf(__shfl(xa1, k), wv, A);
            B = fmaf(__shfl(xb1, k), wv, B);
        }
        float sA = A, sB = B;
#pragma unroll
        for (int off = 32; off > 0; off >>= 1) { sA += __shfl_xor(sA, off); sB += __shfl_xor(sB, off); }
        float mA = sA * (1.0f / 64.0f), mB = sB * (1.0f / 64.0f);
        float dA = A - mA, dB = B - mB;
        float vA2 = dA * dA, vB2 = dB * dB;
#pragma unroll
        for (int off = 32; off > 0; off >>= 1) { vA2 += __shfl_xor(vA2, off); vB2 += __shfl_xor(vB2, off); }
        float rA = rsqrtf(vA2 * (1.0f / 64.0f) + LNEPS);
        float rB = rsqrtf(vB2 * (1.0f / 64.0f) + LNEPS);
        float vA = g * dA * rA + be; vA = vA > 0.f ? vA : vA * 0.f;
        float vB = g * dB * rB + be; vB = vB > 0.f ? vB : vB * 0.f;
        float oA = bias2, oB = bias2;
#pragma unroll 8
        for (int k = 0; k < 64; ++k) {
            float wv = w2s[k * 64 + lane];
            oA = fmaf(__shfl(vA, k), wv, oA);
            oB = fmaf(__shfl(vB, k), wv, oB);
        }
        h0[(size_t)na * HIDF + lane] = f2bf(oA);
        if (vb) h0[(size_t)nb2 * HIDF + lane] = f2bf(oB);
    }
}

// ---------------- CSR build ----------------
__global__ void deg_init_k(int* __restrict__ deg) {
    int i = blockIdx.x * 256 + threadIdx.x;
    if (i < N_NODES) deg[i] = 1;  // self-loop
}
__global__ void deg_count_k(const int* __restrict__ dstI, int* __restrict__ deg) {
    int i = blockIdx.x * 256 + threadIdx.x;
    if (i < E_EDGES) atomicAdd(&deg[dstI[i]], 1);
}
__global__ __launch_bounds__(SCAN_T) void scan_k(const int* __restrict__ deg,
                                                 int* __restrict__ rowp, int* __restrict__ cursor) {
    int tid = threadIdx.x, lane = tid & 63, wv = tid >> 6;
    int c0 = tid * SCAN_CHUNK; if (c0 > N_NODES) c0 = N_NODES;
    int c1 = c0 + SCAN_CHUNK; if (c1 > N_NODES) c1 = N_NODES;
    int s = 0;
    for (int i = c0; i < c1; ++i) s += deg[i];
    int inc = s;
#pragma unroll
    for (int off = 1; off < 64; off <<= 1) { int t = __shfl_up(inc, off); if (lane >= off) inc += t; }
    __shared__ int wsum[SCAN_T / 64];
    if (lane == 63) wsum[wv] = inc;
    __syncthreads();
    int wo = 0;
    for (int w = 0; w < wv; ++w) wo += wsum[w];
    int run = inc - s + wo;
    for (int i = c0; i < c1; ++i) { rowp[i] = run; cursor[i] = run; run += deg[i]; }
    if (tid == SCAN_T - 1) rowp[N_NODES] = run;
}
__global__ void fill_k(const int* __restrict__ srcI, const int* __restrict__ dstI,
                       int* __restrict__ cursor, int* __restrict__ colx) {
    int i = blockIdx.x * 256 + threadIdx.x;
    if (i >= E_EDGES + N_NODES) return;
    int s, d;
    if (i < E_EDGES) { s = srcI[i]; d = dstI[i]; } else { s = i - E_EDGES; d = s; }
    int slot = atomicAdd(&cursor[d], 1);
    colx[slot] = s;
}

// ---------------- MFMA matmul: C[M,256] = A[M,K] @ W[K,256], Wt is W^T [256,K] ----------------
// 128x128 block tile, 4 waves (2x2), each wave 4x4 MFMA 16x16x32 bf16 tiles.
// LDS stride 72 shorts = 144 B (16B-aligned, 2-way banking = free).
__global__ __launch_bounds__(256) void mfma_mm_k(
    const unsigned short* __restrict__ A, const unsigned short* __restrict__ Wt,
    unsigned short* __restrict__ C, int M, int K) {
    __shared__ unsigned short As[128 * 72];
    __shared__ unsigned short Bs[128 * 72];
    int tid = threadIdx.x;
    int wave = tid >> 6, lane = tid & 63;
    int wm = wave >> 1, wn = wave & 1;
    int row0 = blockIdx.y * 128, col0 = blockIdx.x * 128;
    int q = lane >> 4, l = lane & 15;
    f32x4 acc[4][4];
#pragma unroll
    for (int a = 0; a < 4; ++a)
#pragma unroll
        for (int b = 0; b < 4; ++b) acc[a][b] = (f32x4){0.f, 0.f, 0.f, 0.f};
    for (int kb = 0; kb < K; kb += 64) {
#pragma unroll
        for (int it = 0; it < 4; ++it) {
            int cid = it * 256 + tid;
            int r = cid >> 3, kc = cid & 7;
            int gr = row0 + r;
            uint4 v = make_uint4(0, 0, 0, 0);
            if (gr < M) v = *(const uint4*)(A + (size_t)gr * K + kb + kc * 8);
            *(uint4*)&As[r * 72 + kc * 8] = v;
            int gn = col0 + r;
            uint4 w = *(const uint4*)(Wt + (size_t)gn * K + kb + kc * 8);
            *(uint4*)&Bs[r * 72 + kc * 8] = w;
        }
        __syncthreads();
#pragma unroll
        for (int ks = 0; ks < 64; ks += 32) {
            bf16x8 af[4], bfr[4];
#pragma unroll
            for (int mt = 0; mt < 4; ++mt)
                af[mt] = *(const bf16x8*)&As[(wm * 64 + mt * 16 + l) * 72 + ks + q * 8];
#pragma unroll
            for (int nt = 0; nt < 4; ++nt)
                bfr[nt] = *(const bf16x8*)&Bs[(wn * 64 + nt * 16 + l) * 72 + ks + q * 8];
#pragma unroll
            for (int mt = 0; mt < 4; ++mt)
#pragma unroll
                for (int nt = 0; nt < 4; ++nt)
                    acc[mt][nt] = __builtin_amdgcn_mfma_f32_16x16x32_bf16(
                        af[mt], bfr[nt], acc[mt][nt], 0, 0, 0);
        }
        __syncthreads();
    }
    // epilogue: C/D layout col=lane&15, row=q*4+reg
#pragma unroll
    for (int mt = 0; mt < 4; ++mt) {
#pragma unroll
        for (int r = 0; r < 4; ++r) {
            int grow = row0 + wm * 64 + mt * 16 + q * 4 + r;
            if (grow < M) {
                unsigned short* crow = C + (size_t)grow * D_F + col0 + wn * 64 + l;
#pragma unroll
                for (int nt = 0; nt < 4; ++nt) crow[nt * 16] = f2bf(acc[mt][nt][r]);
            }
        }
    }
}

// ---------------- attention logits ----------------
__global__ __launch_bounds__(256) void att_k(
    const unsigned short* __restrict__ h2, const unsigned short* __restrict__ a_s,
    const unsigned short* __restrict__ a_d, float* __restrict__ alS, float* __restrict__ alD) {
    int tid = threadIdx.x, wave = tid >> 6, lane = tid & 63;
    int n = blockIdx.x * 4 + wave;
    if (n >= N_NODES) return;
    int h = lane >> 4, j = (lane & 15) * 4;
    ushort4 hu = *(const ushort4*)(h2 + (size_t)n * D_F + h * 64 + j);
    ushort4 su = *(const ushort4*)(a_s + h * 64 + j);
    ushort4 du = *(const ushort4*)(a_d + h * 64 + j);
    float h0 = bf2f(hu.x), h1 = bf2f(hu.y), h2v = bf2f(hu.z), h3 = bf2f(hu.w);
    float ps = h0 * bf2f(su.x) + h1 * bf2f(su.y) + h2v * bf2f(su.z) + h3 * bf2f(su.w);
    float pd = h0 * bf2f(du.x) + h1 * bf2f(du.y) + h2v * bf2f(du.z) + h3 * bf2f(du.w);
#pragma unroll
    for (int off = 1; off < 16; off <<= 1) { ps += __shfl_xor(ps, off); pd += __shfl_xor(pd, off); }
    if ((lane & 15) == 0) { alS[n * 4 + h] = ps; alD[n * 4 + h] = pd; }
}

// ---------------- GAT aggregate + bias + ELU: wave per dst node ----------------
__global__ __launch_bounds__(256) void agg_k(
    const unsigned short* __restrict__ h2, const int* __restrict__ rowp, const int* __restrict__ colx,
    const float* __restrict__ alS, const float* __restrict__ alD,
    const unsigned short* __restrict__ bias, unsigned short* __restrict__ out) {
    int tid = threadIdx.x, wave = tid >> 6, lane = tid & 63;
    int n = blockIdx.x * 4 + wave;
    if (n >= N_NODES) return;
    int start = rowp[n], end = rowp[n + 1];
    float4 ad = *(const float4*)(alD + (size_t)n * 4);
    float m0 = -1e30f, m1 = -1e30f, m2 = -1e30f, m3 = -1e30f;
    for (int j = start + lane; j < end; j += 64) {
        int s = colx[j];
        float4 as = *(const float4*)(alS + (size_t)s * 4);
        float e0 = as.x + ad.x; e0 = e0 > 0.f ? e0 : NEG * e0;
        float e1 = as.y + ad.y; e1 = e1 > 0.f ? e1 : NEG * e1;
        float e2 = as.z + ad.z; e2 = e2 > 0.f ? e2 : NEG * e2;
        float e3 = as.w + ad.w; e3 = e3 > 0.f ? e3 : NEG * e3;
        m0 = fmaxf(m0, e0); m1 = fmaxf(m1, e1); m2 = fmaxf(m2, e2); m3 = fmaxf(m3, e3);
    }
#pragma unroll
    for (int off = 1; off < 64; off <<= 1) {
        m0 = fmaxf(m0, __shfl_xor(m0, off));
        m1 = fmaxf(m1, __shfl_xor(m1, off));
        m2 = fmaxf(m2, __shfl_xor(m2, off));
        m3 = fmaxf(m3, __shfl_xor(m3, off));
    }
    float l0 = 0.f, l1 = 0.f, l2 = 0.f, l3 = 0.f;
    for (int j = start + lane; j < end; j += 64) {
        int s = colx[j];
        float4 as = *(const float4*)(alS + (size_t)s * 4);
        float e0 = as.x + ad.x; e0 = e0 > 0.f ? e0 : NEG * e0;
        float e1 = as.y + ad.y; e1 = e1 > 0.f ? e1 : NEG * e1;
        float e2 = as.z + ad.z; e2 = e2 > 0.f ? e2 : NEG * e2;
        float e3 = as.w + ad.w; e3 = e3 > 0.f ? e3 : NEG * e3;
        l0 += __expf(e0 - m0); l1 += __expf(e1 - m1); l2 += __expf(e2 - m2); l3 += __expf(e3 - m3);
    }
#pragma unroll
    for (int off = 1; off < 64; off <<= 1) {
        l0 += __shfl_xor(l0, off); l1 += __shfl_xor(l1, off);
        l2 += __shfl_xor(l2, off); l3 += __shfl_xor(l3, off);
    }
    float r0 = 1.f / (l0 + 1e-16f), r1 = 1.f / (l1 + 1e-16f);
    float r2 = 1.f / (l2 + 1e-16f), r3 = 1.f / (l3 + 1e-16f);
    float a0 = 0.f, a1 = 0.f, a2 = 0.f, a3 = 0.f;
    for (int j = start; j < end; ++j) {
        int s = colx[j];
        float4 as = *(const float4*)(alS + (size_t)s * 4);
        float e0 = as.x + ad.x; e0 = e0 > 0.f ? e0 : NEG * e0; float w0 = __expf(e0 - m0) * r0;
        float e1 = as.y + ad.y; e1 = e1 > 0.f ? e1 : NEG * e1; float w1 = __expf(e1 - m1) * r1;
        float e2 = as.z + ad.z; e2 = e2 > 0.f ? e2 : NEG * e2; float w2 = __expf(e2 - m2) * r2;
        float e3 = as.w + ad.w; e3 = e3 > 0.f ? e3 : NEG * e3; float w3 = __expf(e3 - m3) * r3;
        const unsigned short* hr = h2 + (size_t)s * D_F;
        a0 = fmaf(w0, bf2f(hr[lane]), a0);
        a1 = fmaf(w1, bf2f(hr[64 + lane]), a1);
        a2 = fmaf(w2, bf2f(hr[128 + lane]), a2);
        a3 = fmaf(w3, bf2f(hr[192 + lane]), a3);
    }
    unsigned short* orow = out + (size_t)n * D_F;
    float v0 = a0 + bf2f(bias[lane]);       v0 = v0 > 0.f ? v0 : __expf(v0) - 1.f;
    float v1 = a1 + bf2f(bias[64 + lane]);  v1 = v1 > 0.f ? v1 : __expf(v1) - 1.f;
    float v2 = a2 + bf2f(bias[128 + lane]); v2 = v2 > 0.f ? v2 : __expf(v2) - 1.f;
    float v3 = a3 + bf2f(bias[192 + lane]); v3 = v3 > 0.f ? v3 : __expf(v3) - 1.f;
    orow[lane] = f2bf(v0); orow[64 + lane] = f2bf(v1);
    orow[128 + lane] = f2bf(v2); orow[192 + lane] = f2bf(v3);
}

// ---------------- pool: per-block partial sums ----------------
__global__ __launch_bounds__(256) void pool_k(const unsigned short* __restrict__ h,
                                              const int* __restrict__ batch,
                                              float* __restrict__ part, int* __restrict__ pcnt) {
    __shared__ float sums[GROUPS * D_F];
    __shared__ int cnts[GROUPS];
    int tid = threadIdx.x;
    for (int i = tid; i < GROUPS * D_F; i += 256) sums[i] = 0.f;
    if (tid < GROUPS) cnts[tid] = 0;
    __syncthreads();
    int n0 = blockIdx.x * POOL_CHUNK;
    int n1 = n0 + POOL_CHUNK; if (n1 > N_NODES) n1 = N_NODES;
    for (int n = n0; n < n1; ++n) {
        int b = batch[n];
        sums[b * D_F + tid] += bf2f(h[(size_t)n * D_F + tid]);
        if (tid == 0) cnts[b]++;
    }
    __syncthreads();
    float* po = part + (size_t)blockIdx.x * (GROUPS * D_F);
    for (int i = tid; i < GROUPS * D_F; i += 256) po[i] = sums[i];
    if (tid < GROUPS) pcnt[blockIdx.x * GROUPS + tid] = cnts[tid];
}

// ---------------- reduce partials ----------------
__global__ __launch_bounds__(256) void reduce_k(const float* __restrict__ part,
                                                const int* __restrict__ pcnt,
                                                float* __restrict__ gsum, int* __restrict__ gcnt) {
    int g = blockIdx.x, c = threadIdx.x;
    float s = 0.f;
    for (int b = 0; b < POOL_BLOCKS; ++b) s += part[(size_t)b * (GROUPS * D_F) + g * D_F + c];
    gsum[g * D_F + c] = s;
    if (threadIdx.x < 64) {
        int lane = threadIdx.x;
        int cn = 0;
        for (int b = lane; b < POOL_BLOCKS; b += 64) cn += pcnt[b * GROUPS + g];
#pragma unroll
        for (int off = 1; off < 64; off <<= 1) cn += __shfl_xor(cn, off);
        if (lane == 0) gcnt[g] = cn;
    }
}

// ---------------- decoder ----------------
__global__ __launch_bounds__(256) void dec_k(const float* __restrict__ gsum, const int* __restrict__ gcnt,
    const unsigned short* __restrict__ canon, const int* __restrict__ flag,
    void* __restrict__ outp) {
    const unsigned short* w1 = canon + OFF_DW1;
    const unsigned short* b1 = canon + OFF_DB1;
    const unsigned short* gam = canon + OFF_DG;
    const unsigned short* bet = canon + OFF_DBE;
    const unsigned short* w2 = canon + OFF_DW2;
    const unsigned short* b2 = canon + OFF_DB2;
    int tid = threadIdx.x, grp = blockIdx.x * 4 + (tid >> 6), lane = tid & 63;
    if (grp >= GROUPS) return;
    float inv = 1.0f / fmaxf((float)gcnt[grp], 1.0f);
    float p[4];
#pragma unroll
    for (int i = 0; i < 4; ++i) p[i] = gsum[grp * D_F + i * 64 + lane] * inv;
    float acc = bf2f(b1[lane]);
#pragma unroll
    for (int i = 0; i < 4; ++i)
        for (int k = 0; k < 64; ++k)
            acc = fmaf(__shfl(p[i], k), bf2f(w1[(i * 64 + k) * 64 + lane]), acc);
    float s = acc;
#pragma unroll
    for (int off = 32; off > 0; off >>= 1) s += __shfl_xor(s, off);
    float mean = s * (1.0f / 64.0f);
    float d = acc - mean;
    float vs = d * d;
#pragma unroll
    for (int off = 32; off > 0; off >>= 1) vs += __shfl_xor(vs, off);
    float rstd = rsqrtf(vs * (1.0f / 64.0f) + LNEPS);
    float val = bf2f(gam[lane]) * d * rstd + bf2f(bet[lane]);
    val = val > 0.f ? val : val * 0.f;
    int cl = (lane < OUT_F) ? lane : 0;
    float acc2 = 0.f;
    for (int k = 0; k < 64; ++k) {
        float wv = bf2f(w2[k * OUT_F + cl]);
        acc2 = fmaf(__shfl(val, k), wv, acc2);
    }
    if (lane < OUT_F) {
        float res = acc2 + bf2f(b2[lane]);
        if (*flag == 0) ((unsigned short*)outp)[grp * OUT_F + lane] = f2bf(res);
        else            ((float*)outp)[grp * OUT_F + lane] = res;
    }
}

extern "C" void kernel_launch(void* const* d_in, const int* in_sizes, int n_in,
                              void* d_out, int out_size, void* d_ws, size_t ws_size,
                              hipStream_t stream) {
    const int* ei    = (const int*)d_in[1];
    const int* batch = (const int*)d_in[2];

    char* p = (char*)d_ws;
    unsigned short* canon = (unsigned short*)p; p += (size_t)CANON_TOT * 2 + 16;
    unsigned short* bufA = (unsigned short*)p; p += (size_t)N_NODES * D_F * 2;
    unsigned short* bufB = (unsigned short*)p; p += (size_t)N_NODES * D_F * 2;
    unsigned short* wt0 = (unsigned short*)p; p += (size_t)64 * 256 * 2;
    unsigned short* wt1 = (unsigned short*)p; p += (size_t)256 * 256 * 2;
    unsigned short* wt2 = (unsigned short*)p; p += (size_t)256 * 256 * 2;
    float* alS  = (float*)p; p += (size_t)N_NODES * 4 * 4;
    float* alD  = (float*)p; p += (size_t)N_NODES * 4 * 4;
    float* part = (float*)p; p += (size_t)POOL_BLOCKS * GROUPS * D_F * 4;
    int* pcnt   = (int*)p;   p += (size_t)POOL_BLOCKS * GROUPS * 4;
    float* gsum = (float*)p; p += GROUPS * D_F * 4;
    int* gcnt   = (int*)p;   p += 16 * 4;
    int* deg    = (int*)p;   p += (size_t)N_NODES * 4;
    int* rowp   = (int*)p;   p += (size_t)(N_NODES + 4) * 4;
    int* cursor = (int*)p;   p += (size_t)N_NODES * 4;
    int* colx   = (int*)p;   p += (size_t)(E_EDGES + N_NODES) * 4;
    int* flag   = (int*)p;   p += 16;

    const int* srcI = ei;
    const int* dstI = ei + E_EDGES;

    SP sp;
    sp.q[0] = d_in[0];
    for (int t = 1; t < 25; ++t) sp.q[t] = d_in[t + 2];

    int nwb = (N_NODES + 3) / 4;
    int nb256 = (N_NODES + 255) / 256;

    flag_k<<<1, 64, 0, stream>>>((const unsigned short*)d_in[5], flag);
    convert_k<<<(CANON_TOT + 255) / 256, 256, 0, stream>>>(sp, flag, canon);
    wt_k<<<256, 256, 0, stream>>>(canon, wt0, wt1, wt2);

    encoder_k<<<(N_NODES + 63) / 64, 256, 0, stream>>>(canon, bufA);

    deg_init_k<<<nb256, 256, 0, stream>>>(deg);
    deg_count_k<<<(E_EDGES + 255) / 256, 256, 0, stream>>>(dstI, deg);
    scan_k<<<1, SCAN_T, 0, stream>>>(deg, rowp, cursor);
    fill_k<<<(E_EDGES + N_NODES + 255) / 256, 256, 0, stream>>>(srcI, dstI, cursor, colx);

    dim3 mmg(2, (N_NODES + 127) / 128);
    mfma_mm_k<<<mmg, 256, 0, stream>>>(bufA, wt0, bufB, N_NODES, HIDF);
    att_k<<<nwb, 256, 0, stream>>>(bufB, canon + OFF_C0AS, canon + OFF_C0AD, alS, alD);
    agg_k<<<nwb, 256, 0, stream>>>(bufB, rowp, colx, alS, alD, canon + OFF_C0B, bufA);

    mfma_mm_k<<<mmg, 256, 0, stream>>>(bufA, wt1, bufB, N_NODES, D_F);
    att_k<<<nwb, 256, 0, stream>>>(bufB, canon + OFF_C1AS, canon + OFF_C1AD, alS, alD);
    agg_k<<<nwb, 256, 0, stream>>>(bufB, rowp, colx, alS, alD, canon + OFF_C1B, bufA);

    mfma_mm_k<<<mmg, 256, 0, stream>>>(bufA, wt2, bufB, N_NODES, D_F);
    att_k<<<nwb, 256, 0, stream>>>(bufB, canon + OFF_C2AS, canon + OFF_C2AD, alS, alD);
    agg_k<<<nwb, 256, 0, stream>>>(bufB, rowp, colx, alS, alD, canon + OFF_C2B, bufA);

    pool_k<<<POOL_BLOCKS, 256, 0, stream>>>(bufA, batch, part, pcnt);
    reduce_k<<<GROUPS, 256, 0, stream>>>(part, pcnt, gsum, gcnt);
    dec_k<<<2, 256, 0, stream>>>(gsum, gcnt, canon, flag, d_out);
}

// Round 5
// 804.328 us; speedup vs baseline: 1.3951x; 1.2769x over previous
//
#include <hip/hip_runtime.h>
#include <hip/hip_bf16.h>

#define N_NODES 50000
#define E_EDGES 800000
#define IN_F 128
#define HIDF 64
#define HEADS 4
#define OUT_F 40
#define GROUPS 8
#define D_F 256
#define NEG 0.2f
#define LNEPS 1e-5f
#define POOL_CHUNK 128
#define POOL_BLOCKS ((N_NODES + POOL_CHUNK - 1) / POOL_CHUNK)   // 391
#define SCAN_T 256
#define SCAN_CHUNK ((N_NODES + SCAN_T - 1) / SCAN_T)            // 196

// canonical bf16 parameter buffer: element offsets
#define OFF_X    0
#define OFF_EW1  6400000
#define OFF_EB1  6408192
#define OFF_EG   6408256
#define OFF_EBE  6408320
#define OFF_EW2  6408384
#define OFF_EB2  6412480
#define OFF_C0W  6412544
#define OFF_C0AS 6428928
#define OFF_C0AD 6429184
#define OFF_C0B  6429440
#define OFF_C1W  6429696
#define OFF_C1AS 6495232
#define OFF_C1AD 6495488
#define OFF_C1B  6495744
#define OFF_C2W  6496000
#define OFF_C2AS 6561536
#define OFF_C2AD 6561792
#define OFF_C2B  6562048
#define OFF_DW1  6562304
#define OFF_DB1  6578688
#define OFF_DG   6578752
#define OFF_DBE  6578816
#define OFF_DW2  6578880
#define OFF_DB2  6581440
#define CANON_TOT 6581480

__device__ __constant__ int c_off[26] = {
    OFF_X, OFF_EW1, OFF_EB1, OFF_EG, OFF_EBE, OFF_EW2, OFF_EB2,
    OFF_C0W, OFF_C0AS, OFF_C0AD, OFF_C0B,
    OFF_C1W, OFF_C1AS, OFF_C1AD, OFF_C1B,
    OFF_C2W, OFF_C2AS, OFF_C2AD, OFF_C2B,
    OFF_DW1, OFF_DB1, OFF_DG, OFF_DBE, OFF_DW2, OFF_DB2, CANON_TOT};

typedef __attribute__((ext_vector_type(8))) short bf16x8;
typedef __attribute__((ext_vector_type(4))) float f32x4;

__device__ __forceinline__ float bf2f(unsigned short u) {
    union { unsigned int i; float f; } v; v.i = ((unsigned int)u) << 16; return v.f;
}
__device__ __forceinline__ unsigned short f2bf(float f) {
    union { float f; unsigned int i; } v; v.f = f;
    unsigned int r = v.i + 0x7FFF + ((v.i >> 16) & 1);   // RNE
    return (unsigned short)(r >> 16);
}

// ---------- dtype flag: enc_g is all-ones. bf16 -> 0x3F80; fp32 -> (0x0000,0x3F80) ----------
__global__ void flag_k(const unsigned short* __restrict__ encg, int* __restrict__ flag) {
    if (threadIdx.x == 0 && blockIdx.x == 0) {
        unsigned short a = encg[0], b = encg[1];
        int f = 0;
        if (a == 0x0000 && b == 0x3F80) f = 1;
        *flag = f;
    }
}

// ---------- canonicalize all float tensors into bf16 canon buffer ----------
struct SP { const void* q[25]; };
__global__ __launch_bounds__(256) void convert_k(SP sp, const int* __restrict__ flag,
                                                 unsigned short* __restrict__ canon) {
    int i = blockIdx.x * 256 + threadIdx.x;
    if (i >= CANON_TOT) return;
    int t = 0;
    while (i >= c_off[t + 1]) ++t;
    int j = i - c_off[t];
    const void* s = sp.q[t];
    unsigned short v;
    if (*flag == 0) v = ((const unsigned short*)s)[j];
    else            v = f2bf(((const float*)s)[j]);
    canon[i] = v;
}

// ---------- transposes: conv W [K,256]->[256,K]; enc w1 [128,64]->[64,128]; enc w2 [64,64]->[64,64] ----------
__global__ void wt_k(const unsigned short* __restrict__ canon,
                     unsigned short* __restrict__ wt0, unsigned short* __restrict__ wt1,
                     unsigned short* __restrict__ wt2, unsigned short* __restrict__ w1t,
                     unsigned short* __restrict__ w2t) {
    int i = blockIdx.x * 256 + threadIdx.x;   // 65536 threads
    if (i < 8192) {  // w1 [128,64]
        int k = i >> 6, n = i & 63;
        w1t[n * 128 + k] = canon[OFF_EW1 + k * 64 + n];
    }
    if (i < 4096) {  // w2 [64,64]
        int k = i >> 6, n = i & 63;
        w2t[n * 64 + k] = canon[OFF_EW2 + k * 64 + n];
    }
    if (i < 16384) { // conv0_w [64,256]
        int k = i >> 8, n = i & 255;
        wt0[n * 64 + k] = canon[OFF_C0W + i];
    }
    if (i < 65536) { // conv1/2_w [256,256]
        int k = i >> 8, n = i & 255;
        wt1[n * 256 + k] = canon[OFF_C1W + i];
        wt2[n * 256 + k] = canon[OFF_C2W + i];
    }
}

// ---------------- encoder stage 1: T1 = relu(LN(x@w1+b1)) via MFMA, LN fused in epilogue ----------------
// block = 128 thr (2 waves), BM=128 (64 rows/wave), N=64, K=128
__global__ __launch_bounds__(128) void enc1_k(const unsigned short* __restrict__ canon,
                                              const unsigned short* __restrict__ w1t,
                                              unsigned short* __restrict__ T1) {
    const unsigned short* x = canon + OFF_X;
    __shared__ unsigned short As[128 * 72];
    __shared__ unsigned short Bs[64 * 72];
    int tid = threadIdx.x, wave = tid >> 6, lane = tid & 63;
    int q = lane >> 4, l = lane & 15;
    int row0 = blockIdx.x * 128;
    f32x4 acc[4][4];
#pragma unroll
    for (int a = 0; a < 4; ++a)
#pragma unroll
        for (int b = 0; b < 4; ++b) acc[a][b] = (f32x4){0.f, 0.f, 0.f, 0.f};
    for (int kb = 0; kb < IN_F; kb += 64) {
#pragma unroll
        for (int it = 0; it < 8; ++it) {
            int cid = it * 128 + tid;
            int r = cid >> 3, kc = cid & 7;
            int gr = row0 + r;
            uint4 v = make_uint4(0, 0, 0, 0);
            if (gr < N_NODES) v = *(const uint4*)(x + (size_t)gr * IN_F + kb + kc * 8);
            *(uint4*)&As[r * 72 + kc * 8] = v;
        }
#pragma unroll
        for (int it = 0; it < 4; ++it) {
            int cid = it * 128 + tid;
            int r = cid >> 3, kc = cid & 7;
            uint4 w = *(const uint4*)(w1t + (size_t)r * IN_F + kb + kc * 8);
            *(uint4*)&Bs[r * 72 + kc * 8] = w;
        }
        __syncthreads();
#pragma unroll
        for (int ks = 0; ks < 64; ks += 32) {
            bf16x8 af[4], bfr[4];
#pragma unroll
            for (int mt = 0; mt < 4; ++mt)
                af[mt] = *(const bf16x8*)&As[(wave * 64 + mt * 16 + l) * 72 + ks + q * 8];
#pragma unroll
            for (int nt = 0; nt < 4; ++nt)
                bfr[nt] = *(const bf16x8*)&Bs[(nt * 16 + l) * 72 + ks + q * 8];
#pragma unroll
            for (int mt = 0; mt < 4; ++mt)
#pragma unroll
                for (int nt = 0; nt < 4; ++nt)
                    acc[mt][nt] = __builtin_amdgcn_mfma_f32_16x16x32_bf16(
                        af[mt], bfr[nt], acc[mt][nt], 0, 0, 0);
        }
        __syncthreads();
    }
    float b1c[4], gc[4], bec[4];
#pragma unroll
    for (int nt = 0; nt < 4; ++nt) {
        int c = nt * 16 + l;
        b1c[nt] = bf2f(canon[OFF_EB1 + c]);
        gc[nt]  = bf2f(canon[OFF_EG + c]);
        bec[nt] = bf2f(canon[OFF_EBE + c]);
    }
#pragma unroll
    for (int mt = 0; mt < 4; ++mt) {
#pragma unroll
        for (int r = 0; r < 4; ++r) {
            int grow = row0 + wave * 64 + mt * 16 + q * 4 + r;
            float v0 = acc[mt][0][r] + b1c[0];
            float v1 = acc[mt][1][r] + b1c[1];
            float v2 = acc[mt][2][r] + b1c[2];
            float v3 = acc[mt][3][r] + b1c[3];
            float s = v0 + v1 + v2 + v3;
#pragma unroll
            for (int off = 1; off < 16; off <<= 1) s += __shfl_xor(s, off);
            float mean = s * (1.0f / 64.0f);
            float d0 = v0 - mean, d1 = v1 - mean, d2 = v2 - mean, d3 = v3 - mean;
            float vs = d0 * d0 + d1 * d1 + d2 * d2 + d3 * d3;
#pragma unroll
            for (int off = 1; off < 16; off <<= 1) vs += __shfl_xor(vs, off);
            float rstd = rsqrtf(vs * (1.0f / 64.0f) + LNEPS);
            if (grow < N_NODES) {
                unsigned short* trow = T1 + (size_t)grow * HIDF;
                float o0 = gc[0] * d0 * rstd + bec[0]; o0 = fmaxf(o0, 0.f);
                float o1 = gc[1] * d1 * rstd + bec[1]; o1 = fmaxf(o1, 0.f);
                float o2 = gc[2] * d2 * rstd + bec[2]; o2 = fmaxf(o2, 0.f);
                float o3 = gc[3] * d3 * rstd + bec[3]; o3 = fmaxf(o3, 0.f);
                trow[l] = f2bf(o0); trow[16 + l] = f2bf(o1);
                trow[32 + l] = f2bf(o2); trow[48 + l] = f2bf(o3);
            }
        }
    }
}

// ---------------- encoder stage 2: h0 = T1 @ w2 + b2 via MFMA ----------------
__global__ __launch_bounds__(128) void enc2_k(const unsigned short* __restrict__ canon,
                                              const unsigned short* __restrict__ T1,
                                              const unsigned short* __restrict__ w2t,
                                              unsigned short* __restrict__ h0) {
    __shared__ unsigned short As[128 * 72];
    __shared__ unsigned short Bs[64 * 72];
    int tid = threadIdx.x, wave = tid >> 6, lane = tid & 63;
    int q = lane >> 4, l = lane & 15;
    int row0 = blockIdx.x * 128;
    f32x4 acc[4][4];
#pragma unroll
    for (int a = 0; a < 4; ++a)
#pragma unroll
        for (int b = 0; b < 4; ++b) acc[a][b] = (f32x4){0.f, 0.f, 0.f, 0.f};
#pragma unroll
    for (int it = 0; it < 8; ++it) {
        int cid = it * 128 + tid;
        int r = cid >> 3, kc = cid & 7;
        int gr = row0 + r;
        uint4 v = make_uint4(0, 0, 0, 0);
        if (gr < N_NODES) v = *(const uint4*)(T1 + (size_t)gr * HIDF + kc * 8);
        *(uint4*)&As[r * 72 + kc * 8] = v;
    }
#pragma unroll
    for (int it = 0; it < 4; ++it) {
        int cid = it * 128 + tid;
        int r = cid >> 3, kc = cid & 7;
        uint4 w = *(const uint4*)(w2t + (size_t)r * HIDF + kc * 8);
        *(uint4*)&Bs[r * 72 + kc * 8] = w;
    }
    __syncthreads();
#pragma unroll
    for (int ks = 0; ks < 64; ks += 32) {
        bf16x8 af[4], bfr[4];
#pragma unroll
        for (int mt = 0; mt < 4; ++mt)
            af[mt] = *(const bf16x8*)&As[(wave * 64 + mt * 16 + l) * 72 + ks + q * 8];
#pragma unroll
        for (int nt = 0; nt < 4; ++nt)
            bfr[nt] = *(const bf16x8*)&Bs[(nt * 16 + l) * 72 + ks + q * 8];
#pragma unroll
        for (int mt = 0; mt < 4; ++mt)
#pragma unroll
            for (int nt = 0; nt < 4; ++nt)
                acc[mt][nt] = __builtin_amdgcn_mfma_f32_16x16x32_bf16(
                    af[mt], bfr[nt], acc[mt][nt], 0, 0, 0);
    }
    float b2c[4];
#pragma unroll
    for (int nt = 0; nt < 4; ++nt) b2c[nt] = bf2f(canon[OFF_EB2 + nt * 16 + l]);
#pragma unroll
    for (int mt = 0; mt < 4; ++mt) {
#pragma unroll
        for (int r = 0; r < 4; ++r) {
            int grow = row0 + wave * 64 + mt * 16 + q * 4 + r;
            if (grow < N_NODES) {
                unsigned short* hrow = h0 + (size_t)grow * HIDF;
#pragma unroll
                for (int nt = 0; nt < 4; ++nt)
                    hrow[nt * 16 + l] = f2bf(acc[mt][nt][r] + b2c[nt]);
            }
        }
    }
}

// ---------------- CSR build ----------------
__global__ void deg_init_k(int* __restrict__ deg) {
    int i = blockIdx.x * 256 + threadIdx.x;
    if (i < N_NODES) deg[i] = 1;  // self-loop
}
__global__ void deg_count_k(const int* __restrict__ dstI, int* __restrict__ deg) {
    int i = blockIdx.x * 256 + threadIdx.x;
    if (i < E_EDGES) atomicAdd(&deg[dstI[i]], 1);
}
__global__ __launch_bounds__(SCAN_T) void scan_k(const int* __restrict__ deg,
                                                 int* __restrict__ rowp, int* __restrict__ cursor) {
    int tid = threadIdx.x, lane = tid & 63, wv = tid >> 6;
    int c0 = tid * SCAN_CHUNK; if (c0 > N_NODES) c0 = N_NODES;
    int c1 = c0 + SCAN_CHUNK; if (c1 > N_NODES) c1 = N_NODES;
    int s = 0;
    for (int i = c0; i < c1; ++i) s += deg[i];
    int inc = s;
#pragma unroll
    for (int off = 1; off < 64; off <<= 1) { int t = __shfl_up(inc, off); if (lane >= off) inc += t; }
    __shared__ int wsum[SCAN_T / 64];
    if (lane == 63) wsum[wv] = inc;
    __syncthreads();
    int wo = 0;
    for (int w = 0; w < wv; ++w) wo += wsum[w];
    int run = inc - s + wo;
    for (int i = c0; i < c1; ++i) { rowp[i] = run; cursor[i] = run; run += deg[i]; }
    if (tid == SCAN_T - 1) rowp[N_NODES] = run;
}
__global__ void fill_k(const int* __restrict__ srcI, const int* __restrict__ dstI,
                       int* __restrict__ cursor, int* __restrict__ colx) {
    int i = blockIdx.x * 256 + threadIdx.x;
    if (i >= E_EDGES + N_NODES) return;
    int s, d;
    if (i < E_EDGES) { s = srcI[i]; d = dstI[i]; } else { s = i - E_EDGES; d = s; }
    int slot = atomicAdd(&cursor[d], 1);
    colx[slot] = s;
}

// ---------------- MFMA matmul: C[M,256] = A[M,K] @ W[K,256], Wt is W^T [256,K] ----------------
__global__ __launch_bounds__(256) void mfma_mm_k(
    const unsigned short* __restrict__ A, const unsigned short* __restrict__ Wt,
    unsigned short* __restrict__ C, int M, int K) {
    __shared__ unsigned short As[128 * 72];
    __shared__ unsigned short Bs[128 * 72];
    int tid = threadIdx.x;
    int wave = tid >> 6, lane = tid & 63;
    int wm = wave >> 1, wn = wave & 1;
    int row0 = blockIdx.y * 128, col0 = blockIdx.x * 128;
    int q = lane >> 4, l = lane & 15;
    f32x4 acc[4][4];
#pragma unroll
    for (int a = 0; a < 4; ++a)
#pragma unroll
        for (int b = 0; b < 4; ++b) acc[a][b] = (f32x4){0.f, 0.f, 0.f, 0.f};
    for (int kb = 0; kb < K; kb += 64) {
#pragma unroll
        for (int it = 0; it < 4; ++it) {
            int cid = it * 256 + tid;
            int r = cid >> 3, kc = cid & 7;
            int gr = row0 + r;
            uint4 v = make_uint4(0, 0, 0, 0);
            if (gr < M) v = *(const uint4*)(A + (size_t)gr * K + kb + kc * 8);
            *(uint4*)&As[r * 72 + kc * 8] = v;
            int gn = col0 + r;
            uint4 w = *(const uint4*)(Wt + (size_t)gn * K + kb + kc * 8);
            *(uint4*)&Bs[r * 72 + kc * 8] = w;
        }
        __syncthreads();
#pragma unroll
        for (int ks = 0; ks < 64; ks += 32) {
            bf16x8 af[4], bfr[4];
#pragma unroll
            for (int mt = 0; mt < 4; ++mt)
                af[mt] = *(const bf16x8*)&As[(wm * 64 + mt * 16 + l) * 72 + ks + q * 8];
#pragma unroll
            for (int nt = 0; nt < 4; ++nt)
                bfr[nt] = *(const bf16x8*)&Bs[(wn * 64 + nt * 16 + l) * 72 + ks + q * 8];
#pragma unroll
            for (int mt = 0; mt < 4; ++mt)
#pragma unroll
                for (int nt = 0; nt < 4; ++nt)
                    acc[mt][nt] = __builtin_amdgcn_mfma_f32_16x16x32_bf16(
                        af[mt], bfr[nt], acc[mt][nt], 0, 0, 0);
        }
        __syncthreads();
    }
#pragma unroll
    for (int mt = 0; mt < 4; ++mt) {
#pragma unroll
        for (int r = 0; r < 4; ++r) {
            int grow = row0 + wm * 64 + mt * 16 + q * 4 + r;
            if (grow < M) {
                unsigned short* crow = C + (size_t)grow * D_F + col0 + wn * 64 + l;
#pragma unroll
                for (int nt = 0; nt < 4; ++nt) crow[nt * 16] = f2bf(acc[mt][nt][r]);
            }
        }
    }
}

// ---------------- attention logits ----------------
__global__ __launch_bounds__(256) void att_k(
    const unsigned short* __restrict__ h2, const unsigned short* __restrict__ a_s,
    const unsigned short* __restrict__ a_d, float* __restrict__ alS, float* __restrict__ alD) {
    int tid = threadIdx.x, wave = tid >> 6, lane = tid & 63;
    int n = blockIdx.x * 4 + wave;
    if (n >= N_NODES) return;
    int h = lane >> 4, j = (lane & 15) * 4;
    ushort4 hu = *(const ushort4*)(h2 + (size_t)n * D_F + h * 64 + j);
    ushort4 su = *(const ushort4*)(a_s + h * 64 + j);
    ushort4 du = *(const ushort4*)(a_d + h * 64 + j);
    float h0 = bf2f(hu.x), h1 = bf2f(hu.y), h2v = bf2f(hu.z), h3 = bf2f(hu.w);
    float ps = h0 * bf2f(su.x) + h1 * bf2f(su.y) + h2v * bf2f(su.z) + h3 * bf2f(su.w);
    float pd = h0 * bf2f(du.x) + h1 * bf2f(du.y) + h2v * bf2f(du.z) + h3 * bf2f(du.w);
#pragma unroll
    for (int off = 1; off < 16; off <<= 1) { ps += __shfl_xor(ps, off); pd += __shfl_xor(pd, off); }
    if ((lane & 15) == 0) { alS[n * 4 + h] = ps; alD[n * 4 + h] = pd; }
}

// ---------------- GAT aggregate: online-softmax pass + ushort4-gather pass ----------------
__global__ __launch_bounds__(256) void agg_k(
    const unsigned short* __restrict__ h2, const int* __restrict__ rowp, const int* __restrict__ colx,
    const float* __restrict__ alS, const float* __restrict__ alD,
    const unsigned short* __restrict__ bias, unsigned short* __restrict__ out) {
    int tid = threadIdx.x, wave = tid >> 6, lane = tid & 63;
    int n = blockIdx.x * 4 + wave;
    if (n >= N_NODES) return;
    int start = rowp[n], end = rowp[n + 1];
    float4 ad = *(const float4*)(alD + (size_t)n * 4);
    // pass 1: online per-head (m, l), lanes strided over edges
    float m0 = -1e30f, m1 = -1e30f, m2 = -1e30f, m3 = -1e30f;
    float l0 = 0.f, l1 = 0.f, l2 = 0.f, l3 = 0.f;
    for (int j = start + lane; j < end; j += 64) {
        int s = colx[j];
        float4 as = *(const float4*)(alS + (size_t)s * 4);
        float e0 = as.x + ad.x; e0 = e0 > 0.f ? e0 : NEG * e0;
        float e1 = as.y + ad.y; e1 = e1 > 0.f ? e1 : NEG * e1;
        float e2 = as.z + ad.z; e2 = e2 > 0.f ? e2 : NEG * e2;
        float e3 = as.w + ad.w; e3 = e3 > 0.f ? e3 : NEG * e3;
        float t;
        t = fmaxf(m0, e0); l0 = l0 * __expf(m0 - t) + __expf(e0 - t); m0 = t;
        t = fmaxf(m1, e1); l1 = l1 * __expf(m1 - t) + __expf(e1 - t); m1 = t;
        t = fmaxf(m2, e2); l2 = l2 * __expf(m2 - t) + __expf(e2 - t); m2 = t;
        t = fmaxf(m3, e3); l3 = l3 * __expf(m3 - t) + __expf(e3 - t); m3 = t;
    }
#pragma unroll
    for (int off = 1; off < 64; off <<= 1) {
        float mo, lo, t;
        mo = __shfl_xor(m0, off); lo = __shfl_xor(l0, off);
        t = fmaxf(m0, mo); l0 = l0 * __expf(m0 - t) + lo * __expf(mo - t); m0 = t;
        mo = __shfl_xor(m1, off); lo = __shfl_xor(l1, off);
        t = fmaxf(m1, mo); l1 = l1 * __expf(m1 - t) + lo * __expf(mo - t); m1 = t;
        mo = __shfl_xor(m2, off); lo = __shfl_xor(l2, off);
        t = fmaxf(m2, mo); l2 = l2 * __expf(m2 - t) + lo * __expf(mo - t); m2 = t;
        mo = __shfl_xor(m3, off); lo = __shfl_xor(l3, off);
        t = fmaxf(m3, mo); l3 = l3 * __expf(m3 - t) + lo * __expf(mo - t); m3 = t;
    }
    // per-lane head select: lane covers channels 4*lane..4*lane+3, head = lane>>4
    int h = lane >> 4;
    float mh = (h == 0) ? m0 : (h == 1) ? m1 : (h == 2) ? m2 : m3;
    float lh = (h == 0) ? l0 : (h == 1) ? l1 : (h == 2) ? l2 : l3;
    float adh = (h == 0) ? ad.x : (h == 1) ? ad.y : (h == 2) ? ad.z : ad.w;
    float rh = 1.f / (lh + 1e-16f);
    // pass 2: weighted gather, one ushort4 per lane per edge, 2-edge unroll
    float a0 = 0.f, a1 = 0.f, a2 = 0.f, a3 = 0.f;
    int j = start;
    for (; j + 1 < end; j += 2) {
        int s1 = colx[j], s2 = colx[j + 1];
        float e1 = alS[(size_t)s1 * 4 + h] + adh; e1 = e1 > 0.f ? e1 : NEG * e1;
        float e2 = alS[(size_t)s2 * 4 + h] + adh; e2 = e2 > 0.f ? e2 : NEG * e2;
        float w1 = __expf(e1 - mh) * rh;
        float w2 = __expf(e2 - mh) * rh;
        ushort4 u1 = *(const ushort4*)(h2 + (size_t)s1 * D_F + 4 * lane);
        ushort4 u2 = *(const ushort4*)(h2 + (size_t)s2 * D_F + 4 * lane);
        a0 = fmaf(w1, bf2f(u1.x), a0); a0 = fmaf(w2, bf2f(u2.x), a0);
        a1 = fmaf(w1, bf2f(u1.y), a1); a1 = fmaf(w2, bf2f(u2.y), a1);
        a2 = fmaf(w1, bf2f(u1.z), a2); a2 = fmaf(w2, bf2f(u2.z), a2);
        a3 = fmaf(w1, bf2f(u1.w), a3); a3 = fmaf(w2, bf2f(u2.w), a3);
    }
    if (j < end) {
        int s1 = colx[j];
        float e1 = alS[(size_t)s1 * 4 + h] + adh; e1 = e1 > 0.f ? e1 : NEG * e1;
        float w1 = __expf(e1 - mh) * rh;
        ushort4 u1 = *(const ushort4*)(h2 + (size_t)s1 * D_F + 4 * lane);
        a0 = fmaf(w1, bf2f(u1.x), a0);
        a1 = fmaf(w1, bf2f(u1.y), a1);
        a2 = fmaf(w1, bf2f(u1.z), a2);
        a3 = fmaf(w1, bf2f(u1.w), a3);
    }
    // epilogue: bias + ELU, vectorized
    ushort4 bu = *(const ushort4*)(bias + 4 * lane);
    float v0 = a0 + bf2f(bu.x); v0 = v0 > 0.f ? v0 : __expf(v0) - 1.f;
    float v1 = a1 + bf2f(bu.y); v1 = v1 > 0.f ? v1 : __expf(v1) - 1.f;
    float v2 = a2 + bf2f(bu.z); v2 = v2 > 0.f ? v2 : __expf(v2) - 1.f;
    float v3 = a3 + bf2f(bu.w); v3 = v3 > 0.f ? v3 : __expf(v3) - 1.f;
    ushort4 o;
    o.x = f2bf(v0); o.y = f2bf(v1); o.z = f2bf(v2); o.w = f2bf(v3);
    *(ushort4*)(out + (size_t)n * D_F + 4 * lane) = o;
}

// ---------------- pool: per-block partial sums ----------------
__global__ __launch_bounds__(256) void pool_k(const unsigned short* __restrict__ h,
                                              const int* __restrict__ batch,
                                              float* __restrict__ part, int* __restrict__ pcnt) {
    __shared__ float sums[GROUPS * D_F];
    __shared__ int cnts[GROUPS];
    int tid = threadIdx.x;
    for (int i = tid; i < GROUPS * D_F; i += 256) sums[i] = 0.f;
    if (tid < GROUPS) cnts[tid] = 0;
    __syncthreads();
    int n0 = blockIdx.x * POOL_CHUNK;
    int n1 = n0 + POOL_CHUNK; if (n1 > N_NODES) n1 = N_NODES;
    for (int n = n0; n < n1; ++n) {
        int b = batch[n];
        sums[b * D_F + tid] += bf2f(h[(size_t)n * D_F + tid]);
        if (tid == 0) cnts[b]++;
    }
    __syncthreads();
    float* po = part + (size_t)blockIdx.x * (GROUPS * D_F);
    for (int i = tid; i < GROUPS * D_F; i += 256) po[i] = sums[i];
    if (tid < GROUPS) pcnt[blockIdx.x * GROUPS + tid] = cnts[tid];
}

// ---------------- reduce partials ----------------
__global__ __launch_bounds__(256) void reduce_k(const float* __restrict__ part,
                                                const int* __restrict__ pcnt,
                                                float* __restrict__ gsum, int* __restrict__ gcnt) {
    int g = blockIdx.x, c = threadIdx.x;
    float s = 0.f;
    for (int b = 0; b < POOL_BLOCKS; ++b) s += part[(size_t)b * (GROUPS * D_F) + g * D_F + c];
    gsum[g * D_F + c] = s;
    if (threadIdx.x < 64) {
        int lane = threadIdx.x;
        int cn = 0;
        for (int b = lane; b < POOL_BLOCKS; b += 64) cn += pcnt[b * GROUPS + g];
#pragma unroll
        for (int off = 1; off < 64; off <<= 1) cn += __shfl_xor(cn, off);
        if (lane == 0) gcnt[g] = cn;
    }
}

// ---------------- decoder ----------------
__global__ __launch_bounds__(256) void dec_k(const float* __restrict__ gsum, const int* __restrict__ gcnt,
    const unsigned short* __restrict__ canon, const int* __restrict__ flag,
    void* __restrict__ outp) {
    const unsigned short* w1 = canon + OFF_DW1;
    const unsigned short* b1 = canon + OFF_DB1;
    const unsigned short* gam = canon + OFF_DG;
    const unsigned short* bet = canon + OFF_DBE;
    const unsigned short* w2 = canon + OFF_DW2;
    const unsigned short* b2 = canon + OFF_DB2;
    int tid = threadIdx.x, grp = blockIdx.x * 4 + (tid >> 6), lane = tid & 63;
    if (grp >= GROUPS) return;
    float inv = 1.0f / fmaxf((float)gcnt[grp], 1.0f);
    float p[4];
#pragma unroll
    for (int i = 0; i < 4; ++i) p[i] = gsum[grp * D_F + i * 64 + lane] * inv;
    float acc = bf2f(b1[lane]);
#pragma unroll
    for (int i = 0; i < 4; ++i)
        for (int k = 0; k < 64; ++k)
            acc = fmaf(__shfl(p[i], k), bf2f(w1[(i * 64 + k) * 64 + lane]), acc);
    float s = acc;
#pragma unroll
    for (int off = 32; off > 0; off >>= 1) s += __shfl_xor(s, off);
    float mean = s * (1.0f / 64.0f);
    float d = acc - mean;
    float vs = d * d;
#pragma unroll
    for (int off = 32; off > 0; off >>= 1) vs += __shfl_xor(vs, off);
    float rstd = rsqrtf(vs * (1.0f / 64.0f) + LNEPS);
    float val = bf2f(gam[lane]) * d * rstd + bf2f(bet[lane]);
    val = val > 0.f ? val : val * 0.f;
    int cl = (lane < OUT_F) ? lane : 0;
    float acc2 = 0.f;
    for (int k = 0; k < 64; ++k) {
        float wv = bf2f(w2[k * OUT_F + cl]);
        acc2 = fmaf(__shfl(val, k), wv, acc2);
    }
    if (lane < OUT_F) {
        float res = acc2 + bf2f(b2[lane]);
        if (*flag == 0) ((unsigned short*)outp)[grp * OUT_F + lane] = f2bf(res);
        else            ((float*)outp)[grp * OUT_F + lane] = res;
    }
}

extern "C" void kernel_launch(void* const* d_in, const int* in_sizes, int n_in,
                              void* d_out, int out_size, void* d_ws, size_t ws_size,
                              hipStream_t stream) {
    const int* ei    = (const int*)d_in[1];
    const int* batch = (const int*)d_in[2];

    char* p = (char*)d_ws;
    unsigned short* canon = (unsigned short*)p; p += (size_t)CANON_TOT * 2 + 16;
    unsigned short* bufA = (unsigned short*)p; p += (size_t)N_NODES * D_F * 2;
    unsigned short* bufB = (unsigned short*)p; p += (size_t)N_NODES * D_F * 2;
    unsigned short* wt0 = (unsigned short*)p; p += (size_t)64 * 256 * 2;
    unsigned short* wt1 = (unsigned short*)p; p += (size_t)256 * 256 * 2;
    unsigned short* wt2 = (unsigned short*)p; p += (size_t)256 * 256 * 2;
    unsigned short* w1t = (unsigned short*)p; p += (size_t)64 * 128 * 2;
    unsigned short* w2t = (unsigned short*)p; p += (size_t)64 * 64 * 2;
    float* alS  = (float*)p; p += (size_t)N_NODES * 4 * 4;
    float* alD  = (float*)p; p += (size_t)N_NODES * 4 * 4;
    float* part = (float*)p; p += (size_t)POOL_BLOCKS * GROUPS * D_F * 4;
    int* pcnt   = (int*)p;   p += (size_t)POOL_BLOCKS * GROUPS * 4;
    float* gsum = (float*)p; p += GROUPS * D_F * 4;
    int* gcnt   = (int*)p;   p += 16 * 4;
    int* deg    = (int*)p;   p += (size_t)N_NODES * 4;
    int* rowp   = (int*)p;   p += (size_t)(N_NODES + 4) * 4;
    int* cursor = (int*)p;   p += (size_t)N_NODES * 4;
    int* colx   = (int*)p;   p += (size_t)(E_EDGES + N_NODES) * 4;
    int* flag   = (int*)p;   p += 16;

    const int* srcI = ei;
    const int* dstI = ei + E_EDGES;

    SP sp;
    sp.q[0] = d_in[0];
    for (int t = 1; t < 25; ++t) sp.q[t] = d_in[t + 2];

    int nwb = (N_NODES + 3) / 4;
    int nb256 = (N_NODES + 255) / 256;
    int nb128 = (N_NODES + 127) / 128;

    flag_k<<<1, 64, 0, stream>>>((const unsigned short*)d_in[5], flag);
    convert_k<<<(CANON_TOT + 255) / 256, 256, 0, stream>>>(sp, flag, canon);
    wt_k<<<256, 256, 0, stream>>>(canon, wt0, wt1, wt2, w1t, w2t);

    // encoder as 2 MFMA GEMMs: x->T1 (bufB) with fused LN/relu, T1->h0 (bufA)
    enc1_k<<<nb128, 128, 0, stream>>>(canon, w1t, bufB);
    enc2_k<<<nb128, 128, 0, stream>>>(canon, bufB, w2t, bufA);

    deg_init_k<<<nb256, 256, 0, stream>>>(deg);
    deg_count_k<<<(E_EDGES + 255) / 256, 256, 0, stream>>>(dstI, deg);
    scan_k<<<1, SCAN_T, 0, stream>>>(deg, rowp, cursor);
    fill_k<<<(E_EDGES + N_NODES + 255) / 256, 256, 0, stream>>>(srcI, dstI, cursor, colx);

    dim3 mmg(2, nb128);
    mfma_mm_k<<<mmg, 256, 0, stream>>>(bufA, wt0, bufB, N_NODES, HIDF);
    att_k<<<nwb, 256, 0, stream>>>(bufB, canon + OFF_C0AS, canon + OFF_C0AD, alS, alD);
    agg_k<<<nwb, 256, 0, stream>>>(bufB, rowp, colx, alS, alD, canon + OFF_C0B, bufA);

    mfma_mm_k<<<mmg, 256, 0, stream>>>(bufA, wt1, bufB, N_NODES, D_F);
    att_k<<<nwb, 256, 0, stream>>>(bufB, canon + OFF_C1AS, canon + OFF_C1AD, alS, alD);
    agg_k<<<nwb, 256, 0, stream>>>(bufB, rowp, colx, alS, alD, canon + OFF_C1B, bufA);

    mfma_mm_k<<<mmg, 256, 0, stream>>>(bufA, wt2, bufB, N_NODES, D_F);
    att_k<<<nwb, 256, 0, stream>>>(bufB, canon + OFF_C2AS, canon + OFF_C2AD, alS, alD);
    agg_k<<<nwb, 256, 0, stream>>>(bufB, rowp, colx, alS, alD, canon + OFF_C2B, bufA);

    pool_k<<<POOL_BLOCKS, 256, 0, stream>>>(bufA, batch, part, pcnt);
    reduce_k<<<GROUPS, 256, 0, stream>>>(part, pcnt, gsum, gcnt);
    dec_k<<<2, 256, 0, stream>>>(gsum, gcnt, canon, flag, d_out);
}

// Round 6
// 700.897 us; speedup vs baseline: 1.6010x; 1.1476x over previous
//
#include <hip/hip_runtime.h>
#include <hip/hip_bf16.h>

#define N_NODES 50000
#define E_EDGES 800000
#define IN_F 128
#define HIDF 64
#define HEADS 4
#define OUT_F 40
#define GROUPS 8
#define D_F 256
#define NEG 0.2f
#define LNEPS 1e-5f
#define POOL_CHUNK 128
#define POOL_BLOCKS ((N_NODES + POOL_CHUNK - 1) / POOL_CHUNK)   // 391
#define NB256 ((N_NODES + 255) / 256)                            // 196

// canonical bf16 parameter buffer: element offsets
#define OFF_X    0
#define OFF_EW1  6400000
#define OFF_EB1  6408192
#define OFF_EG   6408256
#define OFF_EBE  6408320
#define OFF_EW2  6408384
#define OFF_EB2  6412480
#define OFF_C0W  6412544
#define OFF_C0AS 6428928
#define OFF_C0AD 6429184
#define OFF_C0B  6429440
#define OFF_C1W  6429696
#define OFF_C1AS 6495232
#define OFF_C1AD 6495488
#define OFF_C1B  6495744
#define OFF_C2W  6496000
#define OFF_C2AS 6561536
#define OFF_C2AD 6561792
#define OFF_C2B  6562048
#define OFF_DW1  6562304
#define OFF_DB1  6578688
#define OFF_DG   6578752
#define OFF_DBE  6578816
#define OFF_DW2  6578880
#define OFF_DB2  6581440
#define CANON_TOT 6581480

__device__ __constant__ int c_off[26] = {
    OFF_X, OFF_EW1, OFF_EB1, OFF_EG, OFF_EBE, OFF_EW2, OFF_EB2,
    OFF_C0W, OFF_C0AS, OFF_C0AD, OFF_C0B,
    OFF_C1W, OFF_C1AS, OFF_C1AD, OFF_C1B,
    OFF_C2W, OFF_C2AS, OFF_C2AD, OFF_C2B,
    OFF_DW1, OFF_DB1, OFF_DG, OFF_DBE, OFF_DW2, OFF_DB2, CANON_TOT};

typedef __attribute__((ext_vector_type(8))) short bf16x8;
typedef __attribute__((ext_vector_type(4))) float f32x4;

__device__ __forceinline__ float bf2f(unsigned short u) {
    union { unsigned int i; float f; } v; v.i = ((unsigned int)u) << 16; return v.f;
}
__device__ __forceinline__ unsigned short f2bf(float f) {
    union { float f; unsigned int i; } v; v.f = f;
    unsigned int r = v.i + 0x7FFF + ((v.i >> 16) & 1);   // RNE
    return (unsigned short)(r >> 16);
}

// ---------- dtype flag: enc_g is all-ones. bf16 -> 0x3F80; fp32 -> (0x0000,0x3F80) ----------
__global__ void flag_k(const unsigned short* __restrict__ encg, int* __restrict__ flag) {
    if (threadIdx.x == 0 && blockIdx.x == 0) {
        unsigned short a = encg[0], b = encg[1];
        int f = 0;
        if (a == 0x0000 && b == 0x3F80) f = 1;
        *flag = f;
    }
}

// ---------- canonicalize all float tensors into bf16 canon buffer ----------
struct SP { const void* q[25]; };
__global__ __launch_bounds__(256) void convert_k(SP sp, const int* __restrict__ flag,
                                                 unsigned short* __restrict__ canon) {
    int i = blockIdx.x * 256 + threadIdx.x;
    if (i >= CANON_TOT) return;
    int t = 0;
    while (i >= c_off[t + 1]) ++t;
    int j = i - c_off[t];
    const void* s = sp.q[t];
    unsigned short v;
    if (*flag == 0) v = ((const unsigned short*)s)[j];
    else            v = f2bf(((const float*)s)[j]);
    canon[i] = v;
}

// ---------- transposes: conv W [K,256]->[256,K]; enc w1 [128,64]->[64,128]; enc w2 [64,64]->[64,64] ----------
__global__ void wt_k(const unsigned short* __restrict__ canon,
                     unsigned short* __restrict__ wt0, unsigned short* __restrict__ wt1,
                     unsigned short* __restrict__ wt2, unsigned short* __restrict__ w1t,
                     unsigned short* __restrict__ w2t) {
    int i = blockIdx.x * 256 + threadIdx.x;   // 65536 threads
    if (i < 8192) {  // w1 [128,64]
        int k = i >> 6, n = i & 63;
        w1t[n * 128 + k] = canon[OFF_EW1 + k * 64 + n];
    }
    if (i < 4096) {  // w2 [64,64]
        int k = i >> 6, n = i & 63;
        w2t[n * 64 + k] = canon[OFF_EW2 + k * 64 + n];
    }
    if (i < 16384) { // conv0_w [64,256]
        int k = i >> 8, n = i & 255;
        wt0[n * 64 + k] = canon[OFF_C0W + i];
    }
    if (i < 65536) { // conv1/2_w [256,256]
        int k = i >> 8, n = i & 255;
        wt1[n * 256 + k] = canon[OFF_C1W + i];
        wt2[n * 256 + k] = canon[OFF_C2W + i];
    }
}

// ---------------- encoder stage 1: T1 = relu(LN(x@w1+b1)) via MFMA, LN fused in epilogue ----------------
__global__ __launch_bounds__(128) void enc1_k(const unsigned short* __restrict__ canon,
                                              const unsigned short* __restrict__ w1t,
                                              unsigned short* __restrict__ T1) {
    const unsigned short* x = canon + OFF_X;
    __shared__ unsigned short As[128 * 72];
    __shared__ unsigned short Bs[64 * 72];
    int tid = threadIdx.x, wave = tid >> 6, lane = tid & 63;
    int q = lane >> 4, l = lane & 15;
    int row0 = blockIdx.x * 128;
    f32x4 acc[4][4];
#pragma unroll
    for (int a = 0; a < 4; ++a)
#pragma unroll
        for (int b = 0; b < 4; ++b) acc[a][b] = (f32x4){0.f, 0.f, 0.f, 0.f};
    for (int kb = 0; kb < IN_F; kb += 64) {
#pragma unroll
        for (int it = 0; it < 8; ++it) {
            int cid = it * 128 + tid;
            int r = cid >> 3, kc = cid & 7;
            int gr = row0 + r;
            uint4 v = make_uint4(0, 0, 0, 0);
            if (gr < N_NODES) v = *(const uint4*)(x + (size_t)gr * IN_F + kb + kc * 8);
            *(uint4*)&As[r * 72 + kc * 8] = v;
        }
#pragma unroll
        for (int it = 0; it < 4; ++it) {
            int cid = it * 128 + tid;
            int r = cid >> 3, kc = cid & 7;
            uint4 w = *(const uint4*)(w1t + (size_t)r * IN_F + kb + kc * 8);
            *(uint4*)&Bs[r * 72 + kc * 8] = w;
        }
        __syncthreads();
#pragma unroll
        for (int ks = 0; ks < 64; ks += 32) {
            bf16x8 af[4], bfr[4];
#pragma unroll
            for (int mt = 0; mt < 4; ++mt)
                af[mt] = *(const bf16x8*)&As[(wave * 64 + mt * 16 + l) * 72 + ks + q * 8];
#pragma unroll
            for (int nt = 0; nt < 4; ++nt)
                bfr[nt] = *(const bf16x8*)&Bs[(nt * 16 + l) * 72 + ks + q * 8];
#pragma unroll
            for (int mt = 0; mt < 4; ++mt)
#pragma unroll
                for (int nt = 0; nt < 4; ++nt)
                    acc[mt][nt] = __builtin_amdgcn_mfma_f32_16x16x32_bf16(
                        af[mt], bfr[nt], acc[mt][nt], 0, 0, 0);
        }
        __syncthreads();
    }
    float b1c[4], gc[4], bec[4];
#pragma unroll
    for (int nt = 0; nt < 4; ++nt) {
        int c = nt * 16 + l;
        b1c[nt] = bf2f(canon[OFF_EB1 + c]);
        gc[nt]  = bf2f(canon[OFF_EG + c]);
        bec[nt] = bf2f(canon[OFF_EBE + c]);
    }
#pragma unroll
    for (int mt = 0; mt < 4; ++mt) {
#pragma unroll
        for (int r = 0; r < 4; ++r) {
            int grow = row0 + wave * 64 + mt * 16 + q * 4 + r;
            float v0 = acc[mt][0][r] + b1c[0];
            float v1 = acc[mt][1][r] + b1c[1];
            float v2 = acc[mt][2][r] + b1c[2];
            float v3 = acc[mt][3][r] + b1c[3];
            float s = v0 + v1 + v2 + v3;
#pragma unroll
            for (int off = 1; off < 16; off <<= 1) s += __shfl_xor(s, off);
            float mean = s * (1.0f / 64.0f);
            float d0 = v0 - mean, d1 = v1 - mean, d2 = v2 - mean, d3 = v3 - mean;
            float vs = d0 * d0 + d1 * d1 + d2 * d2 + d3 * d3;
#pragma unroll
            for (int off = 1; off < 16; off <<= 1) vs += __shfl_xor(vs, off);
            float rstd = rsqrtf(vs * (1.0f / 64.0f) + LNEPS);
            if (grow < N_NODES) {
                unsigned short* trow = T1 + (size_t)grow * HIDF;
                float o0 = gc[0] * d0 * rstd + bec[0]; o0 = fmaxf(o0, 0.f);
                float o1 = gc[1] * d1 * rstd + bec[1]; o1 = fmaxf(o1, 0.f);
                float o2 = gc[2] * d2 * rstd + bec[2]; o2 = fmaxf(o2, 0.f);
                float o3 = gc[3] * d3 * rstd + bec[3]; o3 = fmaxf(o3, 0.f);
                trow[l] = f2bf(o0); trow[16 + l] = f2bf(o1);
                trow[32 + l] = f2bf(o2); trow[48 + l] = f2bf(o3);
            }
        }
    }
}

// ---------------- encoder stage 2: h0 = T1 @ w2 + b2 via MFMA ----------------
__global__ __launch_bounds__(128) void enc2_k(const unsigned short* __restrict__ canon,
                                              const unsigned short* __restrict__ T1,
                                              const unsigned short* __restrict__ w2t,
                                              unsigned short* __restrict__ h0) {
    __shared__ unsigned short As[128 * 72];
    __shared__ unsigned short Bs[64 * 72];
    int tid = threadIdx.x, wave = tid >> 6, lane = tid & 63;
    int q = lane >> 4, l = lane & 15;
    int row0 = blockIdx.x * 128;
    f32x4 acc[4][4];
#pragma unroll
    for (int a = 0; a < 4; ++a)
#pragma unroll
        for (int b = 0; b < 4; ++b) acc[a][b] = (f32x4){0.f, 0.f, 0.f, 0.f};
#pragma unroll
    for (int it = 0; it < 8; ++it) {
        int cid = it * 128 + tid;
        int r = cid >> 3, kc = cid & 7;
        int gr = row0 + r;
        uint4 v = make_uint4(0, 0, 0, 0);
        if (gr < N_NODES) v = *(const uint4*)(T1 + (size_t)gr * HIDF + kc * 8);
        *(uint4*)&As[r * 72 + kc * 8] = v;
    }
#pragma unroll
    for (int it = 0; it < 4; ++it) {
        int cid = it * 128 + tid;
        int r = cid >> 3, kc = cid & 7;
        uint4 w = *(const uint4*)(w2t + (size_t)r * HIDF + kc * 8);
        *(uint4*)&Bs[r * 72 + kc * 8] = w;
    }
    __syncthreads();
#pragma unroll
    for (int ks = 0; ks < 64; ks += 32) {
        bf16x8 af[4], bfr[4];
#pragma unroll
        for (int mt = 0; mt < 4; ++mt)
            af[mt] = *(const bf16x8*)&As[(wave * 64 + mt * 16 + l) * 72 + ks + q * 8];
#pragma unroll
        for (int nt = 0; nt < 4; ++nt)
            bfr[nt] = *(const bf16x8*)&Bs[(nt * 16 + l) * 72 + ks + q * 8];
#pragma unroll
        for (int mt = 0; mt < 4; ++mt)
#pragma unroll
            for (int nt = 0; nt < 4; ++nt)
                acc[mt][nt] = __builtin_amdgcn_mfma_f32_16x16x32_bf16(
                    af[mt], bfr[nt], acc[mt][nt], 0, 0, 0);
    }
    float b2c[4];
#pragma unroll
    for (int nt = 0; nt < 4; ++nt) b2c[nt] = bf2f(canon[OFF_EB2 + nt * 16 + l]);
#pragma unroll
    for (int mt = 0; mt < 4; ++mt) {
#pragma unroll
        for (int r = 0; r < 4; ++r) {
            int grow = row0 + wave * 64 + mt * 16 + q * 4 + r;
            if (grow < N_NODES) {
                unsigned short* hrow = h0 + (size_t)grow * HIDF;
#pragma unroll
                for (int nt = 0; nt < 4; ++nt)
                    hrow[nt * 16 + l] = f2bf(acc[mt][nt][r] + b2c[nt]);
            }
        }
    }
}

// ---------------- CSR build ----------------
__global__ void deg_init_k(int* __restrict__ deg) {
    int i = blockIdx.x * 256 + threadIdx.x;
    if (i < N_NODES) deg[i] = 1;  // self-loop
}
__global__ void deg_count_k(const int* __restrict__ dstI, int* __restrict__ deg) {
    int i = blockIdx.x * 256 + threadIdx.x;
    if (i < E_EDGES) atomicAdd(&deg[dstI[i]], 1);
}
// 3-phase parallel exclusive scan of deg[N] -> rowp/cursor (+rowp[N]=total)
__global__ __launch_bounds__(256) void scan1_k(const int* __restrict__ deg, int* __restrict__ excl,
                                               int* __restrict__ bsums) {
    int tid = threadIdx.x, lane = tid & 63, wv = tid >> 6;
    int gid = blockIdx.x * 256 + tid;
    int v = (gid < N_NODES) ? deg[gid] : 0;
    int inc = v;
#pragma unroll
    for (int off = 1; off < 64; off <<= 1) { int t = __shfl_up(inc, off); if (lane >= off) inc += t; }
    __shared__ int wsum[4];
    if (lane == 63) wsum[wv] = inc;
    __syncthreads();
    int wo = 0;
    for (int w = 0; w < wv; ++w) wo += wsum[w];
    int incl = inc + wo;
    if (gid < N_NODES) excl[gid] = incl - v;
    if (tid == 255) bsums[blockIdx.x] = incl;
}
__global__ __launch_bounds__(256) void scan2_k(const int* __restrict__ bsums, int* __restrict__ boff,
                                               int* __restrict__ totalp) {
    int tid = threadIdx.x, lane = tid & 63, wv = tid >> 6;
    int v = (tid < NB256) ? bsums[tid] : 0;
    int inc = v;
#pragma unroll
    for (int off = 1; off < 64; off <<= 1) { int t = __shfl_up(inc, off); if (lane >= off) inc += t; }
    __shared__ int wsum[4];
    if (lane == 63) wsum[wv] = inc;
    __syncthreads();
    int wo = 0;
    for (int w = 0; w < wv; ++w) wo += wsum[w];
    int incl = inc + wo;
    if (tid < NB256) boff[tid] = incl - v;
    if (tid == 255) *totalp = incl;
}
__global__ void scan3_k(const int* __restrict__ excl, const int* __restrict__ boff,
                        int* __restrict__ rowp, int* __restrict__ cursor) {
    int i = blockIdx.x * 256 + threadIdx.x;
    if (i < N_NODES) { int r = excl[i] + boff[i >> 8]; rowp[i] = r; cursor[i] = r; }
}
__global__ void fill_k(const int* __restrict__ srcI, const int* __restrict__ dstI,
                       int* __restrict__ cursor, int* __restrict__ colx) {
    int i = blockIdx.x * 256 + threadIdx.x;
    if (i >= E_EDGES + N_NODES) return;
    int s, d;
    if (i < E_EDGES) { s = srcI[i]; d = dstI[i]; } else { s = i - E_EDGES; d = s; }
    int slot = atomicAdd(&cursor[d], 1);
    colx[slot] = s;
}

// ---------------- MFMA matmul: C[M,256] = A[M,K] @ W[K,256], Wt is W^T [256,K] ----------------
__global__ __launch_bounds__(256) void mfma_mm_k(
    const unsigned short* __restrict__ A, const unsigned short* __restrict__ Wt,
    unsigned short* __restrict__ C, int M, int K) {
    __shared__ unsigned short As[128 * 72];
    __shared__ unsigned short Bs[128 * 72];
    int tid = threadIdx.x;
    int wave = tid >> 6, lane = tid & 63;
    int wm = wave >> 1, wn = wave & 1;
    int row0 = blockIdx.y * 128, col0 = blockIdx.x * 128;
    int q = lane >> 4, l = lane & 15;
    f32x4 acc[4][4];
#pragma unroll
    for (int a = 0; a < 4; ++a)
#pragma unroll
        for (int b = 0; b < 4; ++b) acc[a][b] = (f32x4){0.f, 0.f, 0.f, 0.f};
    for (int kb = 0; kb < K; kb += 64) {
#pragma unroll
        for (int it = 0; it < 4; ++it) {
            int cid = it * 256 + tid;
            int r = cid >> 3, kc = cid & 7;
            int gr = row0 + r;
            uint4 v = make_uint4(0, 0, 0, 0);
            if (gr < M) v = *(const uint4*)(A + (size_t)gr * K + kb + kc * 8);
            *(uint4*)&As[r * 72 + kc * 8] = v;
            int gn = col0 + r;
            uint4 w = *(const uint4*)(Wt + (size_t)gn * K + kb + kc * 8);
            *(uint4*)&Bs[r * 72 + kc * 8] = w;
        }
        __syncthreads();
#pragma unroll
        for (int ks = 0; ks < 64; ks += 32) {
            bf16x8 af[4], bfr[4];
#pragma unroll
            for (int mt = 0; mt < 4; ++mt)
                af[mt] = *(const bf16x8*)&As[(wm * 64 + mt * 16 + l) * 72 + ks + q * 8];
#pragma unroll
            for (int nt = 0; nt < 4; ++nt)
                bfr[nt] = *(const bf16x8*)&Bs[(wn * 64 + nt * 16 + l) * 72 + ks + q * 8];
#pragma unroll
            for (int mt = 0; mt < 4; ++mt)
#pragma unroll
                for (int nt = 0; nt < 4; ++nt)
                    acc[mt][nt] = __builtin_amdgcn_mfma_f32_16x16x32_bf16(
                        af[mt], bfr[nt], acc[mt][nt], 0, 0, 0);
        }
        __syncthreads();
    }
#pragma unroll
    for (int mt = 0; mt < 4; ++mt) {
#pragma unroll
        for (int r = 0; r < 4; ++r) {
            int grow = row0 + wm * 64 + mt * 16 + q * 4 + r;
            if (grow < M) {
                unsigned short* crow = C + (size_t)grow * D_F + col0 + wn * 64 + l;
#pragma unroll
                for (int nt = 0; nt < 4; ++nt) crow[nt * 16] = f2bf(acc[mt][nt][r]);
            }
        }
    }
}

// ---------------- attention logits ----------------
__global__ __launch_bounds__(256) void att_k(
    const unsigned short* __restrict__ h2, const unsigned short* __restrict__ a_s,
    const unsigned short* __restrict__ a_d, float* __restrict__ alS, float* __restrict__ alD) {
    int tid = threadIdx.x, wave = tid >> 6, lane = tid & 63;
    int n = blockIdx.x * 4 + wave;
    if (n >= N_NODES) return;
    int h = lane >> 4, j = (lane & 15) * 4;
    ushort4 hu = *(const ushort4*)(h2 + (size_t)n * D_F + h * 64 + j);
    ushort4 su = *(const ushort4*)(a_s + h * 64 + j);
    ushort4 du = *(const ushort4*)(a_d + h * 64 + j);
    float h0 = bf2f(hu.x), h1 = bf2f(hu.y), h2v = bf2f(hu.z), h3 = bf2f(hu.w);
    float ps = h0 * bf2f(su.x) + h1 * bf2f(su.y) + h2v * bf2f(su.z) + h3 * bf2f(su.w);
    float pd = h0 * bf2f(du.x) + h1 * bf2f(du.y) + h2v * bf2f(du.z) + h3 * bf2f(du.w);
#pragma unroll
    for (int off = 1; off < 16; off <<= 1) { ps += __shfl_xor(ps, off); pd += __shfl_xor(pd, off); }
    if ((lane & 15) == 0) { alS[n * 4 + h] = ps; alD[n * 4 + h] = pd; }
}

// ---------------- GAT aggregate: online-softmax pass + ushort4-gather pass ----------------
__global__ __launch_bounds__(256) void agg_k(
    const unsigned short* __restrict__ h2, const int* __restrict__ rowp, const int* __restrict__ colx,
    const float* __restrict__ alS, const float* __restrict__ alD,
    const unsigned short* __restrict__ bias, unsigned short* __restrict__ out) {
    int tid = threadIdx.x, wave = tid >> 6, lane = tid & 63;
    int n = blockIdx.x * 4 + wave;
    if (n >= N_NODES) return;
    int start = rowp[n], end = rowp[n + 1];
    float4 ad = *(const float4*)(alD + (size_t)n * 4);
    float m0 = -1e30f, m1 = -1e30f, m2 = -1e30f, m3 = -1e30f;
    float l0 = 0.f, l1 = 0.f, l2 = 0.f, l3 = 0.f;
    for (int j = start + lane; j < end; j += 64) {
        int s = colx[j];
        float4 as = *(const float4*)(alS + (size_t)s * 4);
        float e0 = as.x + ad.x; e0 = e0 > 0.f ? e0 : NEG * e0;
        float e1 = as.y + ad.y; e1 = e1 > 0.f ? e1 : NEG * e1;
        float e2 = as.z + ad.z; e2 = e2 > 0.f ? e2 : NEG * e2;
        float e3 = as.w + ad.w; e3 = e3 > 0.f ? e3 : NEG * e3;
        float t;
        t = fmaxf(m0, e0); l0 = l0 * __expf(m0 - t) + __expf(e0 - t); m0 = t;
        t = fmaxf(m1, e1); l1 = l1 * __expf(m1 - t) + __expf(e1 - t); m1 = t;
        t = fmaxf(m2, e2); l2 = l2 * __expf(m2 - t) + __expf(e2 - t); m2 = t;
        t = fmaxf(m3, e3); l3 = l3 * __expf(m3 - t) + __expf(e3 - t); m3 = t;
    }
#pragma unroll
    for (int off = 1; off < 64; off <<= 1) {
        float mo, lo, t;
        mo = __shfl_xor(m0, off); lo = __shfl_xor(l0, off);
        t = fmaxf(m0, mo); l0 = l0 * __expf(m0 - t) + lo * __expf(mo - t); m0 = t;
        mo = __shfl_xor(m1, off); lo = __shfl_xor(l1, off);
        t = fmaxf(m1, mo); l1 = l1 * __expf(m1 - t) + lo * __expf(mo - t); m1 = t;
        mo = __shfl_xor(m2, off); lo = __shfl_xor(l2, off);
        t = fmaxf(m2, mo); l2 = l2 * __expf(m2 - t) + lo * __expf(mo - t); m2 = t;
        mo = __shfl_xor(m3, off); lo = __shfl_xor(l3, off);
        t = fmaxf(m3, mo); l3 = l3 * __expf(m3 - t) + lo * __expf(mo - t); m3 = t;
    }
    int h = lane >> 4;
    float mh = (h == 0) ? m0 : (h == 1) ? m1 : (h == 2) ? m2 : m3;
    float lh = (h == 0) ? l0 : (h == 1) ? l1 : (h == 2) ? l2 : l3;
    float adh = (h == 0) ? ad.x : (h == 1) ? ad.y : (h == 2) ? ad.z : ad.w;
    float rh = 1.f / (lh + 1e-16f);
    float a0 = 0.f, a1 = 0.f, a2 = 0.f, a3 = 0.f;
    int j = start;
    for (; j + 1 < end; j += 2) {
        int s1 = colx[j], s2 = colx[j + 1];
        float e1 = alS[(size_t)s1 * 4 + h] + adh; e1 = e1 > 0.f ? e1 : NEG * e1;
        float e2 = alS[(size_t)s2 * 4 + h] + adh; e2 = e2 > 0.f ? e2 : NEG * e2;
        float w1 = __expf(e1 - mh) * rh;
        float w2 = __expf(e2 - mh) * rh;
        ushort4 u1 = *(const ushort4*)(h2 + (size_t)s1 * D_F + 4 * lane);
        ushort4 u2 = *(const ushort4*)(h2 + (size_t)s2 * D_F + 4 * lane);
        a0 = fmaf(w1, bf2f(u1.x), a0); a0 = fmaf(w2, bf2f(u2.x), a0);
        a1 = fmaf(w1, bf2f(u1.y), a1); a1 = fmaf(w2, bf2f(u2.y), a1);
        a2 = fmaf(w1, bf2f(u1.z), a2); a2 = fmaf(w2, bf2f(u2.z), a2);
        a3 = fmaf(w1, bf2f(u1.w), a3); a3 = fmaf(w2, bf2f(u2.w), a3);
    }
    if (j < end) {
        int s1 = colx[j];
        float e1 = alS[(size_t)s1 * 4 + h] + adh; e1 = e1 > 0.f ? e1 : NEG * e1;
        float w1 = __expf(e1 - mh) * rh;
        ushort4 u1 = *(const ushort4*)(h2 + (size_t)s1 * D_F + 4 * lane);
        a0 = fmaf(w1, bf2f(u1.x), a0);
        a1 = fmaf(w1, bf2f(u1.y), a1);
        a2 = fmaf(w1, bf2f(u1.z), a2);
        a3 = fmaf(w1, bf2f(u1.w), a3);
    }
    ushort4 bu = *(const ushort4*)(bias + 4 * lane);
    float v0 = a0 + bf2f(bu.x); v0 = v0 > 0.f ? v0 : __expf(v0) - 1.f;
    float v1 = a1 + bf2f(bu.y); v1 = v1 > 0.f ? v1 : __expf(v1) - 1.f;
    float v2 = a2 + bf2f(bu.z); v2 = v2 > 0.f ? v2 : __expf(v2) - 1.f;
    float v3 = a3 + bf2f(bu.w); v3 = v3 > 0.f ? v3 : __expf(v3) - 1.f;
    ushort4 o;
    o.x = f2bf(v0); o.y = f2bf(v1); o.z = f2bf(v2); o.w = f2bf(v3);
    *(ushort4*)(out + (size_t)n * D_F + 4 * lane) = o;
}

// ---------------- pool: per-block partial sums ----------------
__global__ __launch_bounds__(256) void pool_k(const unsigned short* __restrict__ h,
                                              const int* __restrict__ batch,
                                              float* __restrict__ part, int* __restrict__ pcnt) {
    __shared__ float sums[GROUPS * D_F];
    __shared__ int cnts[GROUPS];
    int tid = threadIdx.x;
    for (int i = tid; i < GROUPS * D_F; i += 256) sums[i] = 0.f;
    if (tid < GROUPS) cnts[tid] = 0;
    __syncthreads();
    int n0 = blockIdx.x * POOL_CHUNK;
    int n1 = n0 + POOL_CHUNK; if (n1 > N_NODES) n1 = N_NODES;
    for (int n = n0; n < n1; ++n) {
        int b = batch[n];
        sums[b * D_F + tid] += bf2f(h[(size_t)n * D_F + tid]);
        if (tid == 0) cnts[b]++;
    }
    __syncthreads();
    float* po = part + (size_t)blockIdx.x * (GROUPS * D_F);
    for (int i = tid; i < GROUPS * D_F; i += 256) po[i] = sums[i];
    if (tid < GROUPS) pcnt[blockIdx.x * GROUPS + tid] = cnts[tid];
}

// ---------------- reduce partials ----------------
__global__ __launch_bounds__(256) void reduce_k(const float* __restrict__ part,
                                                const int* __restrict__ pcnt,
                                                float* __restrict__ gsum, int* __restrict__ gcnt) {
    int g = blockIdx.x, c = threadIdx.x;
    float s = 0.f;
    for (int b = 0; b < POOL_BLOCKS; ++b) s += part[(size_t)b * (GROUPS * D_F) + g * D_F + c];
    gsum[g * D_F + c] = s;
    if (threadIdx.x < 64) {
        int lane = threadIdx.x;
        int cn = 0;
        for (int b = lane; b < POOL_BLOCKS; b += 64) cn += pcnt[b * GROUPS + g];
#pragma unroll
        for (int off = 1; off < 64; off <<= 1) cn += __shfl_xor(cn, off);
        if (lane == 0) gcnt[g] = cn;
    }
}

// ---------------- decoder ----------------
__global__ __launch_bounds__(256) void dec_k(const float* __restrict__ gsum, const int* __restrict__ gcnt,
    const unsigned short* __restrict__ canon, const int* __restrict__ flag,
    void* __restrict__ outp) {
    const unsigned short* w1 = canon + OFF_DW1;
    const unsigned short* b1 = canon + OFF_DB1;
    const unsigned short* gam = canon + OFF_DG;
    const unsigned short* bet = canon + OFF_DBE;
    const unsigned short* w2 = canon + OFF_DW2;
    const unsigned short* b2 = canon + OFF_DB2;
    int tid = threadIdx.x, grp = blockIdx.x * 4 + (tid >> 6), lane = tid & 63;
    if (grp >= GROUPS) return;
    float inv = 1.0f / fmaxf((float)gcnt[grp], 1.0f);
    float p[4];
#pragma unroll
    for (int i = 0; i < 4; ++i) p[i] = gsum[grp * D_F + i * 64 + lane] * inv;
    float acc = bf2f(b1[lane]);
#pragma unroll
    for (int i = 0; i < 4; ++i)
        for (int k = 0; k < 64; ++k)
            acc = fmaf(__shfl(p[i], k), bf2f(w1[(i * 64 + k) * 64 + lane]), acc);
    float s = acc;
#pragma unroll
    for (int off = 32; off > 0; off >>= 1) s += __shfl_xor(s, off);
    float mean = s * (1.0f / 64.0f);
    float d = acc - mean;
    float vs = d * d;
#pragma unroll
    for (int off = 32; off > 0; off >>= 1) vs += __shfl_xor(vs, off);
    float rstd = rsqrtf(vs * (1.0f / 64.0f) + LNEPS);
    float val = bf2f(gam[lane]) * d * rstd + bf2f(bet[lane]);
    val = val > 0.f ? val : val * 0.f;
    int cl = (lane < OUT_F) ? lane : 0;
    float acc2 = 0.f;
    for (int k = 0; k < 64; ++k) {
        float wv = bf2f(w2[k * OUT_F + cl]);
        acc2 = fmaf(__shfl(val, k), wv, acc2);
    }
    if (lane < OUT_F) {
        float res = acc2 + bf2f(b2[lane]);
        if (*flag == 0) ((unsigned short*)outp)[grp * OUT_F + lane] = f2bf(res);
        else            ((float*)outp)[grp * OUT_F + lane] = res;
    }
}

extern "C" void kernel_launch(void* const* d_in, const int* in_sizes, int n_in,
                              void* d_out, int out_size, void* d_ws, size_t ws_size,
                              hipStream_t stream) {
    const int* ei    = (const int*)d_in[1];
    const int* batch = (const int*)d_in[2];

    char* p = (char*)d_ws;
    unsigned short* canon = (unsigned short*)p; p += (size_t)CANON_TOT * 2 + 16;
    unsigned short* bufA = (unsigned short*)p; p += (size_t)N_NODES * D_F * 2;
    unsigned short* bufB = (unsigned short*)p; p += (size_t)N_NODES * D_F * 2;
    unsigned short* wt0 = (unsigned short*)p; p += (size_t)64 * 256 * 2;
    unsigned short* wt1 = (unsigned short*)p; p += (size_t)256 * 256 * 2;
    unsigned short* wt2 = (unsigned short*)p; p += (size_t)256 * 256 * 2;
    unsigned short* w1t = (unsigned short*)p; p += (size_t)64 * 128 * 2;
    unsigned short* w2t = (unsigned short*)p; p += (size_t)64 * 64 * 2;
    float* alS  = (float*)p; p += (size_t)N_NODES * 4 * 4;
    float* alD  = (float*)p; p += (size_t)N_NODES * 4 * 4;
    float* part = (float*)p; p += (size_t)POOL_BLOCKS * GROUPS * D_F * 4;
    int* pcnt   = (int*)p;   p += (size_t)POOL_BLOCKS * GROUPS * 4;
    float* gsum = (float*)p; p += GROUPS * D_F * 4;
    int* gcnt   = (int*)p;   p += 16 * 4;
    int* deg    = (int*)p;   p += (size_t)N_NODES * 4;
    int* excl   = (int*)p;   p += (size_t)N_NODES * 4;
    int* bsums  = (int*)p;   p += 256 * 4;
    int* boff   = (int*)p;   p += 256 * 4;
    int* rowp   = (int*)p;   p += (size_t)(N_NODES + 4) * 4;
    int* cursor = (int*)p;   p += (size_t)N_NODES * 4;
    int* colx   = (int*)p;   p += (size_t)(E_EDGES + N_NODES) * 4;
    int* flag   = (int*)p;   p += 16;

    const int* srcI = ei;
    const int* dstI = ei + E_EDGES;

    SP sp;
    sp.q[0] = d_in[0];
    for (int t = 1; t < 25; ++t) sp.q[t] = d_in[t + 2];

    int nwb = (N_NODES + 3) / 4;
    int nb128 = (N_NODES + 127) / 128;

    flag_k<<<1, 64, 0, stream>>>((const unsigned short*)d_in[5], flag);
    convert_k<<<(CANON_TOT + 255) / 256, 256, 0, stream>>>(sp, flag, canon);
    wt_k<<<256, 256, 0, stream>>>(canon, wt0, wt1, wt2, w1t, w2t);

    enc1_k<<<nb128, 128, 0, stream>>>(canon, w1t, bufB);
    enc2_k<<<nb128, 128, 0, stream>>>(canon, bufB, w2t, bufA);

    deg_init_k<<<NB256, 256, 0, stream>>>(deg);
    deg_count_k<<<(E_EDGES + 255) / 256, 256, 0, stream>>>(dstI, deg);
    scan1_k<<<NB256, 256, 0, stream>>>(deg, excl, bsums);
    scan2_k<<<1, 256, 0, stream>>>(bsums, boff, rowp + N_NODES);
    scan3_k<<<NB256, 256, 0, stream>>>(excl, boff, rowp, cursor);
    fill_k<<<(E_EDGES + N_NODES + 255) / 256, 256, 0, stream>>>(srcI, dstI, cursor, colx);

    dim3 mmg(2, nb128);
    mfma_mm_k<<<mmg, 256, 0, stream>>>(bufA, wt0, bufB, N_NODES, HIDF);
    att_k<<<nwb, 256, 0, stream>>>(bufB, canon + OFF_C0AS, canon + OFF_C0AD, alS, alD);
    agg_k<<<nwb, 256, 0, stream>>>(bufB, rowp, colx, alS, alD, canon + OFF_C0B, bufA);

    mfma_mm_k<<<mmg, 256, 0, stream>>>(bufA, wt1, bufB, N_NODES, D_F);
    att_k<<<nwb, 256, 0, stream>>>(bufB, canon + OFF_C1AS, canon + OFF_C1AD, alS, alD);
    agg_k<<<nwb, 256, 0, stream>>>(bufB, rowp, colx, alS, alD, canon + OFF_C1B, bufA);

    mfma_mm_k<<<mmg, 256, 0, stream>>>(bufA, wt2, bufB, N_NODES, D_F);
    att_k<<<nwb, 256, 0, stream>>>(bufB, canon + OFF_C2AS, canon + OFF_C2AD, alS, alD);
    agg_k<<<nwb, 256, 0, stream>>>(bufB, rowp, colx, alS, alD, canon + OFF_C2B, bufA);

    pool_k<<<POOL_BLOCKS, 256, 0, stream>>>(bufA, batch, part, pcnt);
    reduce_k<<<GROUPS, 256, 0, stream>>>(part, pcnt, gsum, gcnt);
    dec_k<<<2, 256, 0, stream>>>(gsum, gcnt, canon, flag, d_out);
}